// Round 1
// baseline (1913.998 us; speedup 1.0000x reference)
//
#include <hip/hip_runtime.h>
#include <math.h>

#define B_ 4
#define C_ 256
#define CH_ 128
#define NN 4096   // H*W = 64*64

__device__ __forceinline__ float gelu_erf(float x) {
    return 0.5f * x * (1.0f + erff(x * 0.7071067811865476f));
}

// ---------------------------------------------------------------------------
// Kernel 1: three 1x1 projections fused in one launch (z = which*? -> z%3)
// out[b][o][p] = sum_c W[o][c] * X[b][c][p] + bias[o]
// O=128, I=256. TO=32 outputs, TP=512 positions (2/thread). block=256.
// grid: (4096/512=8, 128/32=4, 3*B=12)
// ---------------------------------------------------------------------------
__global__ __launch_bounds__(256) void proj3_kernel(
    const float* __restrict__ in0, const float* __restrict__ in1,
    const float* __restrict__ wq, const float* __restrict__ bq,
    const float* __restrict__ wk, const float* __restrict__ bk,
    const float* __restrict__ wv, const float* __restrict__ bv,
    float* __restrict__ x1, float* __restrict__ x2, float* __restrict__ x3)
{
    const int t = threadIdx.x;
    const int which = blockIdx.z % 3;
    const int b = blockIdx.z / 3;
    const float* X = (which == 2 ? in1 : in0) + (size_t)b * C_ * NN;
    const float* Wm = which == 0 ? wq : (which == 1 ? wk : wv);
    const float* bias = which == 0 ? bq : (which == 1 ? bk : bv);
    float* out = (which == 0 ? x1 : (which == 1 ? x2 : x3)) + (size_t)b * CH_ * NN;
    const int o0 = blockIdx.y * 32;
    const int p = blockIdx.x * 512 + t;

    __shared__ float Wl[32][256];   // 32 KB
    for (int idx = t; idx < 32 * 256; idx += 256)
        Wl[idx >> 8][idx & 255] = Wm[(size_t)(o0 + (idx >> 8)) * 256 + (idx & 255)];
    __syncthreads();

    float acc0[32], acc1[32];
#pragma unroll
    for (int o = 0; o < 32; ++o) { acc0[o] = 0.f; acc1[o] = 0.f; }

    for (int c = 0; c < 256; c += 4) {
        float xa[4], xb[4];
#pragma unroll
        for (int j = 0; j < 4; ++j) {
            xa[j] = X[(c + j) * NN + p];
            xb[j] = X[(c + j) * NN + p + 256];
        }
#pragma unroll
        for (int o = 0; o < 32; ++o) {
            const float4 w = *(const float4*)&Wl[o][c];
            acc0[o] += w.x * xa[0] + w.y * xa[1] + w.z * xa[2] + w.w * xa[3];
            acc1[o] += w.x * xb[0] + w.y * xb[1] + w.z * xb[2] + w.w * xb[3];
        }
    }
#pragma unroll
    for (int o = 0; o < 32; ++o) {
        const float bo = bias[o0 + o];
        out[(size_t)(o0 + o) * NN + p] = acc0[o] + bo;
        out[(size_t)(o0 + o) * NN + p + 256] = acc1[o] + bo;
    }
}

// ---------------------------------------------------------------------------
// Kernel 2: flash attention fp32.
// S[j][k] = sum_i K[i][j]*Q[i][k]; P = softmax_j(S); O[i][k] = sum_j V[i][j]P[j][k]
// Q=x3, K=x2, V=x1, all [B][128][4096]. Q-tile=64 queries, K-tile=64 keys.
// block=512 threads (8 waves). grid (64, B).
// ---------------------------------------------------------------------------
__global__ __launch_bounds__(512) void attn_kernel(
    const float* __restrict__ x1, const float* __restrict__ x2,
    const float* __restrict__ x3, float* __restrict__ x0)
{
    __shared__ float Qs[128][68];   // [i][k]  34816 B
    __shared__ float Ks[128][68];   // [i][j]  34816 B
    __shared__ float Vs[64][132];   // [j][i]  33792 B
    __shared__ float Sb[64][64];    // [j][k]  16384 B (reused as P)
    __shared__ float red[8][64];
    __shared__ float mArr[64], lArr[64], aArr[64];

    const int t = threadIdx.x;
    const int b = blockIdx.y;
    const int k0g = blockIdx.x * 64;

    {   // load Q tile (i-major)
        const float* Qsrc = x3 + (size_t)b * CH_ * NN + k0g;
        for (int idx = t; idx < 128 * 64; idx += 512) {
            const int i = idx >> 6, k = idx & 63;
            Qs[i][k] = Qsrc[(size_t)i * NN + k];
        }
    }
    if (t < 64) { mArr[t] = -1e30f; lArr[t] = 0.f; }

    float acc[4][4];
#pragma unroll
    for (int a = 0; a < 4; ++a)
#pragma unroll
        for (int c = 0; c < 4; ++c) acc[a][c] = 0.f;

    for (int jt = 0; jt < 64; ++jt) {
        const int j0g = jt * 64;
        __syncthreads();   // prev tile phase B done (also covers Q load, init)
        {   // load K (i-major) and V (j-major) tiles
            const float* Ksrc = x2 + (size_t)b * CH_ * NN + j0g;
            const float* Vsrc = x1 + (size_t)b * CH_ * NN + j0g;
            for (int idx = t; idx < 128 * 64; idx += 512) {
                const int i = idx >> 6, j = idx & 63;
                Ks[i][j] = Ksrc[(size_t)i * NN + j];
                Vs[j][i] = Vsrc[(size_t)i * NN + j];
            }
        }
        __syncthreads();
        {   // phase A: scores, 2j x 4k register block per thread
            const int j0l = (t >> 4) * 2;
            const int k0l = (t & 15) * 4;
            float s00 = 0, s01 = 0, s02 = 0, s03 = 0;
            float s10 = 0, s11 = 0, s12 = 0, s13 = 0;
            for (int i = 0; i < 128; ++i) {
                const float2 kv = *(const float2*)&Ks[i][j0l];
                const float4 qv = *(const float4*)&Qs[i][k0l];
                s00 += kv.x * qv.x; s01 += kv.x * qv.y; s02 += kv.x * qv.z; s03 += kv.x * qv.w;
                s10 += kv.y * qv.x; s11 += kv.y * qv.y; s12 += kv.y * qv.z; s13 += kv.y * qv.w;
            }
            *(float4*)&Sb[j0l][k0l]     = make_float4(s00, s01, s02, s03);
            *(float4*)&Sb[j0l + 1][k0l] = make_float4(s10, s11, s12, s13);
        }
        __syncthreads();
        {   // column max partials
            const int k = t & 63, g = t >> 6;
            float pm = -1e30f;
#pragma unroll
            for (int jj = 0; jj < 8; ++jj) pm = fmaxf(pm, Sb[g * 8 + jj][k]);
            red[g][k] = pm;
        }
        __syncthreads();
        if (t < 64) {   // online-softmax state update
            const float m_old = mArr[t];
            float tm = red[0][t];
#pragma unroll
            for (int g = 1; g < 8; ++g) tm = fmaxf(tm, red[g][t]);
            const float m_new = fmaxf(m_old, tm);
            aArr[t] = __expf(m_old - m_new);
            mArr[t] = m_new;
        }
        __syncthreads();
        {   // exponentiate in place + partial sums
            const int k = t & 63, g = t >> 6;
            const float m = mArr[k];
            float ps = 0.f;
#pragma unroll
            for (int jj = 0; jj < 8; ++jj) {
                const float p = __expf(Sb[g * 8 + jj][k] - m);
                Sb[g * 8 + jj][k] = p;
                ps += p;
            }
            red[g][k] = ps;
        }
        __syncthreads();
        if (t < 64) {
            float s = 0.f;
#pragma unroll
            for (int g = 0; g < 8; ++g) s += red[g][t];
            lArr[t] = lArr[t] * aArr[t] + s;
        }
        {   // phase B: O += V * P, 4i x 4k register block
            const int k0l = (t & 15) * 4;
            const int i0 = (t >> 4) * 4;
            const float a0 = aArr[k0l], a1 = aArr[k0l + 1], a2 = aArr[k0l + 2], a3 = aArr[k0l + 3];
#pragma unroll
            for (int ii = 0; ii < 4; ++ii) {
                acc[ii][0] *= a0; acc[ii][1] *= a1; acc[ii][2] *= a2; acc[ii][3] *= a3;
            }
            for (int j = 0; j < 64; ++j) {
                const float4 pv = *(const float4*)&Sb[j][k0l];
                const float4 vv = *(const float4*)&Vs[j][i0];
                acc[0][0] += vv.x * pv.x; acc[0][1] += vv.x * pv.y; acc[0][2] += vv.x * pv.z; acc[0][3] += vv.x * pv.w;
                acc[1][0] += vv.y * pv.x; acc[1][1] += vv.y * pv.y; acc[1][2] += vv.y * pv.z; acc[1][3] += vv.y * pv.w;
                acc[2][0] += vv.z * pv.x; acc[2][1] += vv.z * pv.y; acc[2][2] += vv.z * pv.z; acc[2][3] += vv.z * pv.w;
                acc[3][0] += vv.w * pv.x; acc[3][1] += vv.w * pv.y; acc[3][2] += vv.w * pv.z; acc[3][3] += vv.w * pv.w;
            }
        }
    }
    __syncthreads();
    {   // finalize: normalize by l and store
        const int k0l = (t & 15) * 4;
        const int i0 = (t >> 4) * 4;
        float linv[4];
#pragma unroll
        for (int kk = 0; kk < 4; ++kk) linv[kk] = 1.f / lArr[k0l + kk];
        float* dst = x0 + (size_t)b * CH_ * NN + k0g;
#pragma unroll
        for (int ii = 0; ii < 4; ++ii)
#pragma unroll
            for (int kk = 0; kk < 4; ++kk)
                dst[(size_t)(i0 + ii) * NN + k0l + kk] = acc[ii][kk] * linv[kk];
    }
}

// ---------------------------------------------------------------------------
// Kernel 3: conv_o (1x1, 128->256) + BN + GELU -> x0g
// grid (8, 8, 4), block 256
// ---------------------------------------------------------------------------
__global__ __launch_bounds__(256) void convo_kernel(
    const float* __restrict__ x0, const float* __restrict__ wo,
    const float* __restrict__ bo,
    const float* __restrict__ g, const float* __restrict__ bb,
    const float* __restrict__ mm, const float* __restrict__ vv,
    float* __restrict__ x0g)
{
    const int t = threadIdx.x;
    const int b = blockIdx.z;
    const int o0 = blockIdx.y * 32;
    const int p = blockIdx.x * 512 + t;
    const float* X = x0 + (size_t)b * CH_ * NN;

    __shared__ float Wl[32][128];   // 16 KB
    for (int idx = t; idx < 32 * 128; idx += 256)
        Wl[idx >> 7][idx & 127] = wo[(size_t)(o0 + (idx >> 7)) * 128 + (idx & 127)];
    __syncthreads();

    float acc0[32], acc1[32];
#pragma unroll
    for (int o = 0; o < 32; ++o) { acc0[o] = 0.f; acc1[o] = 0.f; }

    for (int c = 0; c < 128; c += 4) {
        float xa[4], xb[4];
#pragma unroll
        for (int j = 0; j < 4; ++j) {
            xa[j] = X[(c + j) * NN + p];
            xb[j] = X[(c + j) * NN + p + 256];
        }
#pragma unroll
        for (int o = 0; o < 32; ++o) {
            const float4 w = *(const float4*)&Wl[o][c];
            acc0[o] += w.x * xa[0] + w.y * xa[1] + w.z * xa[2] + w.w * xa[3];
            acc1[o] += w.x * xb[0] + w.y * xb[1] + w.z * xb[2] + w.w * xb[3];
        }
    }
#pragma unroll
    for (int o = 0; o < 32; ++o) {
        const int og = o0 + o;
        const float sc = g[og] * rsqrtf(vv[og] + 1e-5f);
        const float sh = bb[og] - mm[og] * sc;
        const float r0 = (acc0[o] + bo[og]) * sc + sh;
        const float r1 = (acc1[o] + bo[og]) * sc + sh;
        x0g[(size_t)(b * C_ + og) * NN + p] = gelu_erf(r0);
        x0g[(size_t)(b * C_ + og) * NN + p + 256] = gelu_erf(r1);
    }
}

// ---------------------------------------------------------------------------
// Kernel 4: 3x3 conv (SAME) + BN + GELU. I = 512 (virtual concat) or 256.
// One block = one output row y (64 px) x 64 output channels x one batch.
// grid (64, 4, 4), block 256. Thread: 2 x-positions, 8 output channels.
// ---------------------------------------------------------------------------
template <int I>
__global__ __launch_bounds__(256) void conv3x3_kernel(
    const float* __restrict__ inA, const float* __restrict__ inB,
    const float* __restrict__ Wm, const float* __restrict__ bias,
    const float* __restrict__ bng, const float* __restrict__ bnb,
    const float* __restrict__ bnm, const float* __restrict__ bnv,
    float* __restrict__ out)
{
    const int t = threadIdx.x;
    const int y = blockIdx.x;
    const int o0 = blockIdx.y * 64;
    const int b = blockIdx.z;

    __shared__ float Wl[16 * 9 * 64];    // [ci][k][o]  36864 B
    __shared__ float tile[16][3][68];    // x padded: [0]=x-1, [1..64]=x, [65]=x+64

    const int xp = (t & 31) * 2;   // x pair base
    const int og = t >> 5;         // 0..7 -> o = o0 + og*8 + oo
    float acc[8][2];
#pragma unroll
    for (int i = 0; i < 8; ++i) { acc[i][0] = 0.f; acc[i][1] = 0.f; }

    for (int c0 = 0; c0 < I; c0 += 16) {
        __syncthreads();
        {   // weight chunk: per-o contiguous run of 144 floats
            const int o = t >> 2, sub = t & 3;
            const float* wsrc = Wm + (size_t)(o0 + o) * (I * 9) + c0 * 9;
#pragma unroll
            for (int s = 0; s < 36; ++s) {
                const int lin = sub + s * 4;   // 0..143 = ci*9 + k
                Wl[lin * 64 + o] = wsrc[lin];
            }
        }
        {   // input tile: 16 ci x 3 rows x 64 x (+zero pads)
            const int x = t & 63, rr = t >> 6;
            for (int q = rr; q < 48; q += 4) {
                const int ci = q / 3, r = q % 3;
                const int yy = y + r - 1;
                const int cg = c0 + ci;
                float v = 0.f;
                if (yy >= 0 && yy < 64) {
                    const float* src = (I == 512 && cg >= 256)
                        ? (inB + (size_t)(b * 256 + (cg - 256)) * NN)
                        : (inA + (size_t)(b * 256 + cg) * NN);
                    v = src[yy * 64 + x];
                }
                tile[ci][r][1 + x] = v;
                if (x == 0)  tile[ci][r][0]  = 0.f;
                if (x == 63) tile[ci][r][65] = 0.f;
            }
        }
        __syncthreads();
        for (int ci = 0; ci < 16; ++ci) {
#pragma unroll
            for (int dy = 0; dy < 3; ++dy) {
#pragma unroll
                for (int dx = 0; dx < 3; ++dx) {
                    const float v0 = tile[ci][dy][xp + dx];
                    const float v1 = tile[ci][dy][xp + dx + 1];
                    const float* wr = &Wl[(ci * 9 + dy * 3 + dx) * 64 + og * 8];
                    const float4 wa = *(const float4*)&wr[0];
                    const float4 wb = *(const float4*)&wr[4];
                    acc[0][0] += wa.x * v0; acc[0][1] += wa.x * v1;
                    acc[1][0] += wa.y * v0; acc[1][1] += wa.y * v1;
                    acc[2][0] += wa.z * v0; acc[2][1] += wa.z * v1;
                    acc[3][0] += wa.w * v0; acc[3][1] += wa.w * v1;
                    acc[4][0] += wb.x * v0; acc[4][1] += wb.x * v1;
                    acc[5][0] += wb.y * v0; acc[5][1] += wb.y * v1;
                    acc[6][0] += wb.z * v0; acc[6][1] += wb.z * v1;
                    acc[7][0] += wb.w * v0; acc[7][1] += wb.w * v1;
                }
            }
        }
    }
    // epilogue: bias + BN + GELU
#pragma unroll
    for (int oo = 0; oo < 8; ++oo) {
        const int o = o0 + og * 8 + oo;
        const float sc = bng[o] * rsqrtf(bnv[o] + 1e-5f);
        const float sh = bnb[o] - bnm[o] * sc;
        const float r0 = (acc[oo][0] + bias[o]) * sc + sh;
        const float r1 = (acc[oo][1] + bias[o]) * sc + sh;
        float2 rr2 = make_float2(gelu_erf(r0), gelu_erf(r1));
        *(float2*)&out[(size_t)(b * C_ + o) * NN + y * 64 + xp] = rr2;
    }
}

// ---------------------------------------------------------------------------
// Kernel 5: out[b][o] = max_p (y1[b][o][p] + x0g[b][o][p])
// grid 1024 (= b*256+o), block 256
// ---------------------------------------------------------------------------
__global__ __launch_bounds__(256) void maxred_kernel(
    const float* __restrict__ y1, const float* __restrict__ x0g,
    float* __restrict__ out)
{
    const int bo = blockIdx.x;
    const float* p1 = y1 + (size_t)bo * NN;
    const float* p2 = x0g + (size_t)bo * NN;
    const int t = threadIdx.x;
    float m = -1e30f;
    for (int i = t * 4; i < NN; i += 1024) {
        const float4 a = *(const float4*)&p1[i];
        const float4 c = *(const float4*)&p2[i];
        m = fmaxf(m, fmaxf(fmaxf(a.x + c.x, a.y + c.y), fmaxf(a.z + c.z, a.w + c.w)));
    }
#pragma unroll
    for (int off = 32; off > 0; off >>= 1) m = fmaxf(m, __shfl_down(m, off));
    __shared__ float sm[4];
    if ((t & 63) == 0) sm[t >> 6] = m;
    __syncthreads();
    if (t == 0) out[bo] = fmaxf(fmaxf(sm[0], sm[1]), fmaxf(sm[2], sm[3]));
}

// ---------------------------------------------------------------------------
extern "C" void kernel_launch(void* const* d_in, const int* in_sizes, int n_in,
                              void* d_out, int out_size, void* d_ws, size_t ws_size,
                              hipStream_t stream)
{
    const float* in0  = (const float*)d_in[0];
    const float* in1  = (const float*)d_in[1];
    const float* w_q  = (const float*)d_in[2];
    const float* b_q  = (const float*)d_in[3];
    const float* w_k  = (const float*)d_in[4];
    const float* b_k  = (const float*)d_in[5];
    const float* w_v  = (const float*)d_in[6];
    const float* b_v  = (const float*)d_in[7];
    const float* w_o  = (const float*)d_in[8];
    const float* b_o  = (const float*)d_in[9];
    const float* bn0g = (const float*)d_in[10];
    const float* bn0b = (const float*)d_in[11];
    const float* bn0m = (const float*)d_in[12];
    const float* bn0v = (const float*)d_in[13];
    const float* cbw0 = (const float*)d_in[14];
    const float* cbb0 = (const float*)d_in[15];
    const float* cb0g = (const float*)d_in[16];
    const float* cb0b = (const float*)d_in[17];
    const float* cb0m = (const float*)d_in[18];
    const float* cb0v = (const float*)d_in[19];
    const float* cbw1 = (const float*)d_in[20];
    const float* cbb1 = (const float*)d_in[21];
    const float* cb1g = (const float*)d_in[22];
    const float* cb1b = (const float*)d_in[23];
    const float* cb1m = (const float*)d_in[24];
    const float* cb1v = (const float*)d_in[25];

    float* ws  = (float*)d_ws;
    float* x1  = ws;                          // [4][128][4096]  2M floats
    float* x2  = ws + (1u << 21);
    float* x3  = ws + (2u << 21);
    float* x0  = ws + (3u << 21);
    float* x0g = ws + (4u << 21);             // [4][256][4096]  4M floats
    float* y0  = ws;                          // reuse x1,x2 (dead after attention)
    float* y1  = ws + (2u << 21);             // reuse x3,x0 (dead after conv_o)
    float* outp = (float*)d_out;

    proj3_kernel<<<dim3(8, 4, 12), 256, 0, stream>>>(in0, in1, w_q, b_q, w_k, b_k, w_v, b_v, x1, x2, x3);
    attn_kernel<<<dim3(64, 4), 512, 0, stream>>>(x1, x2, x3, x0);
    convo_kernel<<<dim3(8, 8, 4), 256, 0, stream>>>(x0, w_o, b_o, bn0g, bn0b, bn0m, bn0v, x0g);
    conv3x3_kernel<512><<<dim3(64, 4, 4), 256, 0, stream>>>(x0g, in0, cbw0, cbb0, cb0g, cb0b, cb0m, cb0v, y0);
    conv3x3_kernel<256><<<dim3(64, 4, 4), 256, 0, stream>>>(y0, nullptr, cbw1, cbb1, cb1g, cb1b, cb1m, cb1v, y1);
    maxred_kernel<<<1024, 256, 0, stream>>>(y1, x0g, outp);
}

// Round 2
// 916.338 us; speedup vs baseline: 2.0887x; 2.0887x over previous
//
#include <hip/hip_runtime.h>
#include <math.h>

#define B_ 4
#define C_ 256
#define CH_ 128
#define NN 4096   // H*W = 64*64

typedef __bf16 bf16x8 __attribute__((ext_vector_type(8)));
typedef float f32x16 __attribute__((ext_vector_type(16)));

__device__ __forceinline__ float gelu_erf(float x) {
    return 0.5f * x * (1.0f + erff(x * 0.7071067811865476f));
}

// ---------------------------------------------------------------------------
// Kernel 1: three 1x1 projections fused in one launch
// ---------------------------------------------------------------------------
__global__ __launch_bounds__(256) void proj3_kernel(
    const float* __restrict__ in0, const float* __restrict__ in1,
    const float* __restrict__ wq, const float* __restrict__ bq,
    const float* __restrict__ wk, const float* __restrict__ bk,
    const float* __restrict__ wv, const float* __restrict__ bv,
    float* __restrict__ x1, float* __restrict__ x2, float* __restrict__ x3)
{
    const int t = threadIdx.x;
    const int which = blockIdx.z % 3;
    const int b = blockIdx.z / 3;
    const float* X = (which == 2 ? in1 : in0) + (size_t)b * C_ * NN;
    const float* Wm = which == 0 ? wq : (which == 1 ? wk : wv);
    const float* bias = which == 0 ? bq : (which == 1 ? bk : bv);
    float* out = (which == 0 ? x1 : (which == 1 ? x2 : x3)) + (size_t)b * CH_ * NN;
    const int o0 = blockIdx.y * 32;
    const int p = blockIdx.x * 512 + t;

    __shared__ float Wl[32][256];
    for (int idx = t; idx < 32 * 256; idx += 256)
        Wl[idx >> 8][idx & 255] = Wm[(size_t)(o0 + (idx >> 8)) * 256 + (idx & 255)];
    __syncthreads();

    float acc0[32], acc1[32];
#pragma unroll
    for (int o = 0; o < 32; ++o) { acc0[o] = 0.f; acc1[o] = 0.f; }

    for (int c = 0; c < 256; c += 4) {
        float xa[4], xb[4];
#pragma unroll
        for (int j = 0; j < 4; ++j) {
            xa[j] = X[(c + j) * NN + p];
            xb[j] = X[(c + j) * NN + p + 256];
        }
#pragma unroll
        for (int o = 0; o < 32; ++o) {
            const float4 w = *(const float4*)&Wl[o][c];
            acc0[o] += w.x * xa[0] + w.y * xa[1] + w.z * xa[2] + w.w * xa[3];
            acc1[o] += w.x * xb[0] + w.y * xb[1] + w.z * xb[2] + w.w * xb[3];
        }
    }
#pragma unroll
    for (int o = 0; o < 32; ++o) {
        const float bo = bias[o0 + o];
        out[(size_t)(o0 + o) * NN + p] = acc0[o] + bo;
        out[(size_t)(o0 + o) * NN + p + 256] = acc1[o] + bo;
    }
}

// ---------------------------------------------------------------------------
// Kernel 2: flash attention fp32 (unchanged from passing baseline)
// ---------------------------------------------------------------------------
__global__ __launch_bounds__(512) void attn_kernel(
    const float* __restrict__ x1, const float* __restrict__ x2,
    const float* __restrict__ x3, float* __restrict__ x0)
{
    __shared__ float Qs[128][68];
    __shared__ float Ks[128][68];
    __shared__ float Vs[64][132];
    __shared__ float Sb[64][64];
    __shared__ float red[8][64];
    __shared__ float mArr[64], lArr[64], aArr[64];

    const int t = threadIdx.x;
    const int b = blockIdx.y;
    const int k0g = blockIdx.x * 64;

    {
        const float* Qsrc = x3 + (size_t)b * CH_ * NN + k0g;
        for (int idx = t; idx < 128 * 64; idx += 512) {
            const int i = idx >> 6, k = idx & 63;
            Qs[i][k] = Qsrc[(size_t)i * NN + k];
        }
    }
    if (t < 64) { mArr[t] = -1e30f; lArr[t] = 0.f; }

    float acc[4][4];
#pragma unroll
    for (int a = 0; a < 4; ++a)
#pragma unroll
        for (int c = 0; c < 4; ++c) acc[a][c] = 0.f;

    for (int jt = 0; jt < 64; ++jt) {
        const int j0g = jt * 64;
        __syncthreads();
        {
            const float* Ksrc = x2 + (size_t)b * CH_ * NN + j0g;
            const float* Vsrc = x1 + (size_t)b * CH_ * NN + j0g;
            for (int idx = t; idx < 128 * 64; idx += 512) {
                const int i = idx >> 6, j = idx & 63;
                Ks[i][j] = Ksrc[(size_t)i * NN + j];
                Vs[j][i] = Vsrc[(size_t)i * NN + j];
            }
        }
        __syncthreads();
        {
            const int j0l = (t >> 4) * 2;
            const int k0l = (t & 15) * 4;
            float s00 = 0, s01 = 0, s02 = 0, s03 = 0;
            float s10 = 0, s11 = 0, s12 = 0, s13 = 0;
            for (int i = 0; i < 128; ++i) {
                const float2 kv = *(const float2*)&Ks[i][j0l];
                const float4 qv = *(const float4*)&Qs[i][k0l];
                s00 += kv.x * qv.x; s01 += kv.x * qv.y; s02 += kv.x * qv.z; s03 += kv.x * qv.w;
                s10 += kv.y * qv.x; s11 += kv.y * qv.y; s12 += kv.y * qv.z; s13 += kv.y * qv.w;
            }
            *(float4*)&Sb[j0l][k0l]     = make_float4(s00, s01, s02, s03);
            *(float4*)&Sb[j0l + 1][k0l] = make_float4(s10, s11, s12, s13);
        }
        __syncthreads();
        {
            const int k = t & 63, g = t >> 6;
            float pm = -1e30f;
#pragma unroll
            for (int jj = 0; jj < 8; ++jj) pm = fmaxf(pm, Sb[g * 8 + jj][k]);
            red[g][k] = pm;
        }
        __syncthreads();
        if (t < 64) {
            const float m_old = mArr[t];
            float tm = red[0][t];
#pragma unroll
            for (int g = 1; g < 8; ++g) tm = fmaxf(tm, red[g][t]);
            const float m_new = fmaxf(m_old, tm);
            aArr[t] = __expf(m_old - m_new);
            mArr[t] = m_new;
        }
        __syncthreads();
        {
            const int k = t & 63, g = t >> 6;
            const float m = mArr[k];
            float ps = 0.f;
#pragma unroll
            for (int jj = 0; jj < 8; ++jj) {
                const float p = __expf(Sb[g * 8 + jj][k] - m);
                Sb[g * 8 + jj][k] = p;
                ps += p;
            }
            red[g][k] = ps;
        }
        __syncthreads();
        if (t < 64) {
            float s = 0.f;
#pragma unroll
            for (int g = 0; g < 8; ++g) s += red[g][t];
            lArr[t] = lArr[t] * aArr[t] + s;
        }
        {
            const int k0l = (t & 15) * 4;
            const int i0 = (t >> 4) * 4;
            const float a0 = aArr[k0l], a1 = aArr[k0l + 1], a2 = aArr[k0l + 2], a3 = aArr[k0l + 3];
#pragma unroll
            for (int ii = 0; ii < 4; ++ii) {
                acc[ii][0] *= a0; acc[ii][1] *= a1; acc[ii][2] *= a2; acc[ii][3] *= a3;
            }
            for (int j = 0; j < 64; ++j) {
                const float4 pv = *(const float4*)&Sb[j][k0l];
                const float4 vv = *(const float4*)&Vs[j][i0];
                acc[0][0] += vv.x * pv.x; acc[0][1] += vv.x * pv.y; acc[0][2] += vv.x * pv.z; acc[0][3] += vv.x * pv.w;
                acc[1][0] += vv.y * pv.x; acc[1][1] += vv.y * pv.y; acc[1][2] += vv.y * pv.z; acc[1][3] += vv.y * pv.w;
                acc[2][0] += vv.z * pv.x; acc[2][1] += vv.z * pv.y; acc[2][2] += vv.z * pv.z; acc[2][3] += vv.z * pv.w;
                acc[3][0] += vv.w * pv.x; acc[3][1] += vv.w * pv.y; acc[3][2] += vv.w * pv.z; acc[3][3] += vv.w * pv.w;
            }
        }
    }
    __syncthreads();
    {
        const int k0l = (t & 15) * 4;
        const int i0 = (t >> 4) * 4;
        float linv[4];
#pragma unroll
        for (int kk = 0; kk < 4; ++kk) linv[kk] = 1.f / lArr[k0l + kk];
        float* dst = x0 + (size_t)b * CH_ * NN + k0g;
#pragma unroll
        for (int ii = 0; ii < 4; ++ii)
#pragma unroll
            for (int kk = 0; kk < 4; ++kk)
                dst[(size_t)(i0 + ii) * NN + k0l + kk] = acc[ii][kk] * linv[kk];
    }
}

// ---------------------------------------------------------------------------
// Kernel 3: conv_o (1x1, 128->256) + BN + GELU -> x0g (fp32 NCHW)
// ---------------------------------------------------------------------------
__global__ __launch_bounds__(256) void convo_kernel(
    const float* __restrict__ x0, const float* __restrict__ wo,
    const float* __restrict__ bo,
    const float* __restrict__ g, const float* __restrict__ bb,
    const float* __restrict__ mm, const float* __restrict__ vv,
    float* __restrict__ x0g)
{
    const int t = threadIdx.x;
    const int b = blockIdx.z;
    const int o0 = blockIdx.y * 32;
    const int p = blockIdx.x * 512 + t;
    const float* X = x0 + (size_t)b * CH_ * NN;

    __shared__ float Wl[32][128];
    for (int idx = t; idx < 32 * 128; idx += 256)
        Wl[idx >> 7][idx & 127] = wo[(size_t)(o0 + (idx >> 7)) * 128 + (idx & 127)];
    __syncthreads();

    float acc0[32], acc1[32];
#pragma unroll
    for (int o = 0; o < 32; ++o) { acc0[o] = 0.f; acc1[o] = 0.f; }

    for (int c = 0; c < 128; c += 4) {
        float xa[4], xb[4];
#pragma unroll
        for (int j = 0; j < 4; ++j) {
            xa[j] = X[(c + j) * NN + p];
            xb[j] = X[(c + j) * NN + p + 256];
        }
#pragma unroll
        for (int o = 0; o < 32; ++o) {
            const float4 w = *(const float4*)&Wl[o][c];
            acc0[o] += w.x * xa[0] + w.y * xa[1] + w.z * xa[2] + w.w * xa[3];
            acc1[o] += w.x * xb[0] + w.y * xb[1] + w.z * xb[2] + w.w * xb[3];
        }
    }
#pragma unroll
    for (int o = 0; o < 32; ++o) {
        const int og = o0 + o;
        const float sc = g[og] * rsqrtf(vv[og] + 1e-5f);
        const float sh = bb[og] - mm[og] * sc;
        const float r0 = (acc0[o] + bo[og]) * sc + sh;
        const float r1 = (acc1[o] + bo[og]) * sc + sh;
        x0g[(size_t)(b * C_ + og) * NN + p] = gelu_erf(r0);
        x0g[(size_t)(b * C_ + og) * NN + p + 256] = gelu_erf(r1);
    }
}

// ---------------------------------------------------------------------------
// Kernel 4: NCHW fp32 -> NHWC bf16 cast/transpose (dst row width 512)
// grid (64 p-tiles, 4 c-tiles, 4 b), block 256
// ---------------------------------------------------------------------------
__global__ __launch_bounds__(256) void nhwc_cast_kernel(
    const float* __restrict__ src, __bf16* __restrict__ dst, int colbase)
{
    __shared__ float Lt[64][65];
    const int t = threadIdx.x;
    const int p0 = blockIdx.x * 64;
    const int c0 = blockIdx.y * 64;
    const int b  = blockIdx.z;
#pragma unroll
    for (int i = 0; i < 16; ++i) {
        int idx = t + i * 256;
        int c = idx >> 6, p = idx & 63;
        Lt[c][p] = src[((size_t)(b * 256 + c0 + c)) * 4096 + p0 + p];
    }
    __syncthreads();
#pragma unroll
    for (int i = 0; i < 16; ++i) {
        int idx = t + i * 256;
        int p = idx >> 6, c = idx & 63;
        dst[((size_t)(b * 4096 + p0 + p)) * 512 + colbase + c0 + c] = (__bf16)Lt[c][p];
    }
}

// ---------------------------------------------------------------------------
// Kernel 5: weight transform: [O][I][3][3] fp32 -> [k9][O][I] bf16 for both convs
// ---------------------------------------------------------------------------
__global__ __launch_bounds__(256) void wtrans_kernel(
    const float* __restrict__ w0, const float* __restrict__ w1,
    __bf16* __restrict__ Wt0, __bf16* __restrict__ Wt1)
{
    int id = blockIdx.x * 256 + threadIdx.x;
    if (id < 256 * 512) {
        int o = id >> 9, ci = id & 511;
        const float* s = w0 + (size_t)id * 9;
#pragma unroll
        for (int k = 0; k < 9; ++k)
            Wt0[((size_t)k * 256 + o) * 512 + ci] = (__bf16)s[k];
    } else {
        int id2 = id - 256 * 512;
        if (id2 < 256 * 256) {
            int o = id2 >> 8, ci = id2 & 255;
            const float* s = w1 + (size_t)id2 * 9;
#pragma unroll
            for (int k = 0; k < 9; ++k)
                Wt1[((size_t)k * 256 + o) * 256 + ci] = (__bf16)s[k];
        }
    }
}

// ---------------------------------------------------------------------------
// Kernel 6: 3x3 conv via MFMA (implicit GEMM), NHWC bf16 in/out, BN+GELU.
// Block: 64 out-ch x 256 positions (4 image rows), 4 waves (each 1 row, 64x64
// tile = 2x2 frags of 32x32). K = ci chunks of 16, double-buffered LDS.
// grid: 256 blocks linear (XCD-aware decode), block 256.
// ---------------------------------------------------------------------------
template<int IC>
__global__ __launch_bounds__(256) void conv3x3_mfma_kernel(
    const __bf16* __restrict__ Xsrc,   // NHWC [4][4096][IC]
    const __bf16* __restrict__ Wt,     // [9][256][IC]
    const float* __restrict__ bias, const float* __restrict__ bng,
    const float* __restrict__ bnb, const float* __restrict__ bnm,
    const float* __restrict__ bnv,
    __bf16* __restrict__ out)          // NHWC [4][4096][256]
{
    constexpr int NC = IC / 16;
    // Wl: [k9][64 o][16 ci] bf16, row stride 32B, swizzle ^((o&7)<<4). 18432 B.
    // Tl: [6 r][66 xh][16 ci] bf16, xh stride 32B, r stride 2304B (256B-mult
    //     so the ^((xh&7)<<4) swizzle stays bijective). 13824 B.
    __shared__ __align__(16) char Wl[2][18432];
    __shared__ __align__(16) char Tl[2][13824];
    __shared__ float scb[64], shb[64], bsb[64];

    const int t = threadIdx.x;
    const int bid = blockIdx.x;
    const int xcd = bid & 7, local = bid >> 3;
    const int combo = xcd * 2 + (local >> 4);   // 0..15 -> (m,b); pins weights per XCD L2
    const int pt = local & 15;
    const int m = combo & 3, b = combo >> 2;
    const int o0 = m * 64;
    const int y0 = pt * 4;

    if (t < 64) {
        const int o = o0 + t;
        const float sc = bng[o] * rsqrtf(bnv[o] + 1e-5f);
        scb[t] = sc; shb[t] = bnb[o] - bnm[o] * sc; bsb[t] = bias[o];
    }

    const int lane = t & 63, w = t >> 6;
    const int l31 = lane & 31, hi = lane >> 5;

    uint4 wreg[5], ireg[3];

    auto loadW = [&](int c0) {
#pragma unroll
        for (int s = 0; s < 5; ++s) {
            int u = t + s * 256;
            if (u < 1152) {
                int g = u & 1, o = (u >> 1) & 63, k9 = u >> 7;
                wreg[s] = *(const uint4*)&Wt[((size_t)(k9 * 256 + o0 + o)) * IC + c0 + g * 8];
            }
        }
    };
    auto loadI = [&](int c0) {
#pragma unroll
        for (int s = 0; s < 3; ++s) {
            int u = t + s * 256;
            int g = u & 1, x = (u >> 1) & 63, r = u >> 7;
            int yy = y0 - 1 + r;
            if (yy >= 0 && yy < 64)
                ireg[s] = *(const uint4*)&Xsrc[((size_t)(b * 4096 + yy * 64 + x)) * IC + c0 + g * 8];
            else
                ireg[s] = make_uint4(0u, 0u, 0u, 0u);
        }
    };
    auto writeW = [&](char* dst) {
#pragma unroll
        for (int s = 0; s < 5; ++s) {
            int u = t + s * 256;
            if (u < 1152) {
                int g = u & 1, o = (u >> 1) & 63, k9 = u >> 7;
                int byte = ((k9 * 64 + o) * 32 + g * 16) ^ ((o & 7) << 4);
                *(uint4*)(dst + byte) = wreg[s];
            }
        }
    };
    auto writeI = [&](char* dst) {
#pragma unroll
        for (int s = 0; s < 3; ++s) {
            int u = t + s * 256;
            int g = u & 1, x = (u >> 1) & 63, r = u >> 7;
            int xh = x + 1;
            int byte = (r * 2304 + xh * 32 + g * 16) ^ ((xh & 7) << 4);
            *(uint4*)(dst + byte) = ireg[s];
        }
        if (t < 24) {   // x halo zeros (xh=0 and 65)
            int g = t & 1, side = (t >> 1) & 1, r = t >> 2;
            int xh = side ? 65 : 0;
            int byte = (r * 2304 + xh * 32 + g * 16) ^ ((xh & 7) << 4);
            *(uint4*)(dst + byte) = make_uint4(0u, 0u, 0u, 0u);
        }
    };

    f32x16 acc[2][2];
#pragma unroll
    for (int i = 0; i < 2; ++i)
#pragma unroll
        for (int j = 0; j < 2; ++j)
#pragma unroll
            for (int e = 0; e < 16; ++e) acc[i][j][e] = 0.f;

    // per-lane fragment address bases (A: row=o_loc, B: col=x position)
    const int Abase = (l31 * 32 + hi * 16) ^ ((l31 & 7) << 4);
    int Bbase[3];
#pragma unroll
    for (int dx = 0; dx < 3; ++dx) {
        int xh = dx + l31;
        Bbase[dx] = (xh * 32 + hi * 16) ^ ((xh & 7) << 4);
    }

    auto compute = [&](const char* Wb, const char* Tb) {
#pragma unroll
        for (int k9 = 0; k9 < 9; ++k9) {
            const int dy = k9 / 3, dx = k9 % 3;
            bf16x8 a0 = *(const bf16x8*)(Wb + k9 * 2048 + Abase);
            bf16x8 a1 = *(const bf16x8*)(Wb + k9 * 2048 + 1024 + Abase);
            const char* Trow = Tb + (w + dy) * 2304;
#pragma unroll
            for (int nx = 0; nx < 2; ++nx) {
                bf16x8 bv = *(const bf16x8*)(Trow + nx * 1024 + Bbase[dx]);
                acc[0][nx] = __builtin_amdgcn_mfma_f32_32x32x16_bf16(a0, bv, acc[0][nx], 0, 0, 0);
                acc[1][nx] = __builtin_amdgcn_mfma_f32_32x32x16_bf16(a1, bv, acc[1][nx], 0, 0, 0);
            }
        }
    };

    // prologue
    loadW(0); loadI(0);
    writeW(Wl[0]); writeI(Tl[0]);
    __syncthreads();
    for (int c = 0; c < NC; ++c) {
        const int cur = c & 1;
        if (c + 1 < NC) { loadW((c + 1) * 16); loadI((c + 1) * 16); }
        compute(Wl[cur], Tl[cur]);
        __syncthreads();
        if (c + 1 < NC) { writeW(Wl[cur ^ 1]); writeI(Tl[cur ^ 1]); }
        __syncthreads();
    }

    // epilogue: bias + BN + GELU, store NHWC bf16
    // C layout (verified): col = lane&31, row = (reg&3) + 8*(reg>>2) + 4*(lane>>5)
#pragma unroll
    for (int mi = 0; mi < 2; ++mi)
#pragma unroll
        for (int nx = 0; nx < 2; ++nx) {
            const int x = nx * 32 + l31;
            const int p = (y0 + w) * 64 + x;
            const size_t rowbase = ((size_t)(b * 4096 + p)) * 256 + o0;
#pragma unroll
            for (int q = 0; q < 4; ++q) {
                const int obase = mi * 32 + q * 8 + hi * 4;
                __bf16 pk[4];
#pragma unroll
                for (int j = 0; j < 4; ++j) {
                    float v = acc[mi][nx][q * 4 + j] + bsb[obase + j];
                    v = v * scb[obase + j] + shb[obase + j];
                    pk[j] = (__bf16)gelu_erf(v);
                }
                *(uint2*)&out[rowbase + obase] = *(const uint2*)pk;
            }
        }
}

// ---------------------------------------------------------------------------
// Kernel 7/8: global max of (y1 + x0) over spatial, two stages
// ---------------------------------------------------------------------------
__global__ __launch_bounds__(256) void maxpart_kernel(
    const __bf16* __restrict__ y1, const __bf16* __restrict__ xt0,
    float* __restrict__ part)   // [4][64][256]
{
    const int o = threadIdx.x;
    const int chunk = blockIdx.x & 63;
    const int b = blockIdx.x >> 6;
    float mx = -1e30f;
    for (int pp = 0; pp < 64; ++pp) {
        int p = chunk * 64 + pp;
        float a = (float)y1[((size_t)(b * 4096 + p)) * 256 + o];
        float c = (float)xt0[((size_t)(b * 4096 + p)) * 512 + o];
        mx = fmaxf(mx, a + c);
    }
    part[((size_t)(b * 64 + chunk)) * 256 + o] = mx;
}

__global__ __launch_bounds__(256) void maxfin_kernel(
    const float* __restrict__ part, float* __restrict__ out)
{
    const int o = threadIdx.x;
    const int b = blockIdx.x;
    float mx = -1e30f;
    for (int c = 0; c < 64; ++c)
        mx = fmaxf(mx, part[((size_t)(b * 64 + c)) * 256 + o]);
    out[b * 256 + o] = mx;
}

// ---------------------------------------------------------------------------
extern "C" void kernel_launch(void* const* d_in, const int* in_sizes, int n_in,
                              void* d_out, int out_size, void* d_ws, size_t ws_size,
                              hipStream_t stream)
{
    const float* in0  = (const float*)d_in[0];
    const float* in1  = (const float*)d_in[1];
    const float* w_q  = (const float*)d_in[2];
    const float* b_q  = (const float*)d_in[3];
    const float* w_k  = (const float*)d_in[4];
    const float* b_k  = (const float*)d_in[5];
    const float* w_v  = (const float*)d_in[6];
    const float* b_v  = (const float*)d_in[7];
    const float* w_o  = (const float*)d_in[8];
    const float* b_o  = (const float*)d_in[9];
    const float* bn0g = (const float*)d_in[10];
    const float* bn0b = (const float*)d_in[11];
    const float* bn0m = (const float*)d_in[12];
    const float* bn0v = (const float*)d_in[13];
    const float* cbw0 = (const float*)d_in[14];
    const float* cbb0 = (const float*)d_in[15];
    const float* cb0g = (const float*)d_in[16];
    const float* cb0b = (const float*)d_in[17];
    const float* cb0m = (const float*)d_in[18];
    const float* cb0v = (const float*)d_in[19];
    const float* cbw1 = (const float*)d_in[20];
    const float* cbb1 = (const float*)d_in[21];
    const float* cb1g = (const float*)d_in[22];
    const float* cb1b = (const float*)d_in[23];
    const float* cb1m = (const float*)d_in[24];
    const float* cb1v = (const float*)d_in[25];

    char* wsb = (char*)d_ws;
    // fp32 stage (first half of pipeline)
    float* x1  = (float*)(wsb + (size_t)0);           // [4][128][4096] 8MB
    float* x2  = (float*)(wsb + ((size_t)8  << 20));
    float* x3  = (float*)(wsb + ((size_t)16 << 20));
    float* x0  = (float*)(wsb + ((size_t)24 << 20));
    float* x0g = (float*)(wsb + ((size_t)32 << 20));  // [4][256][4096] 16MB
    // bf16 stage (overlays regions that are dead by the time they're written)
    __bf16* Xt0 = (__bf16*)(wsb + (size_t)0);          // [4][4096][512] 16MB (after attn)
    __bf16* Wt0 = (__bf16*)(wsb + ((size_t)16 << 20)); // [9][256][512] 2.36MB (after attn)
    __bf16* Wt1 = (__bf16*)(wsb + ((size_t)19 << 20)); // [9][256][256] 1.18MB
    __bf16* y0  = (__bf16*)(wsb + ((size_t)24 << 20)); // [4][4096][256] 8MB (after convo)
    __bf16* y1  = (__bf16*)(wsb + ((size_t)32 << 20)); // [4][4096][256] 8MB (after transB)
    float*  part = (float*)(wsb + ((size_t)40 << 20)); // [4][64][256] 256KB
    float* outp = (float*)d_out;

    proj3_kernel<<<dim3(8, 4, 12), 256, 0, stream>>>(in0, in1, w_q, b_q, w_k, b_k, w_v, b_v, x1, x2, x3);
    attn_kernel<<<dim3(64, 4), 512, 0, stream>>>(x1, x2, x3, x0);
    convo_kernel<<<dim3(8, 8, 4), 256, 0, stream>>>(x0, w_o, b_o, bn0g, bn0b, bn0m, bn0v, x0g);
    wtrans_kernel<<<768, 256, 0, stream>>>(cbw0, cbw1, Wt0, Wt1);
    nhwc_cast_kernel<<<dim3(64, 4, 4), 256, 0, stream>>>(in0, Xt0, 256);
    nhwc_cast_kernel<<<dim3(64, 4, 4), 256, 0, stream>>>(x0g, Xt0, 0);
    conv3x3_mfma_kernel<512><<<256, 256, 0, stream>>>(Xt0, Wt0, cbb0, cb0g, cb0b, cb0m, cb0v, y0);
    conv3x3_mfma_kernel<256><<<256, 256, 0, stream>>>(y0, Wt1, cbb1, cb1g, cb1b, cb1m, cb1v, y1);
    maxpart_kernel<<<256, 256, 0, stream>>>(y1, Xt0, part);
    maxfin_kernel<<<4, 256, 0, stream>>>(part, outp);
}

// Round 3
// 455.642 us; speedup vs baseline: 4.2007x; 2.0111x over previous
//
#include <hip/hip_runtime.h>
#include <math.h>

#define B_ 4
#define C_ 256
#define CH_ 128
#define NN 4096   // H*W = 64*64

typedef __bf16 bf16x8 __attribute__((ext_vector_type(8)));
typedef float f32x16 __attribute__((ext_vector_type(16)));
typedef unsigned int u32;

__device__ __forceinline__ float gelu_erf(float x) {
    return 0.5f * x * (1.0f + erff(x * 0.7071067811865476f));
}

// ---------------------------------------------------------------------------
// Kernel 1: three 1x1 projections; outputs bf16 in attention-friendly layouts:
//   which==0 (x1=V): ch-major [b][128][4096]
//   which==1 (x2=K): pos-major [b][4096][128]
//   which==2 (x3=Q): pos-major [b][4096][128]
// ---------------------------------------------------------------------------
__global__ __launch_bounds__(256) void proj3_kernel(
    const float* __restrict__ in0, const float* __restrict__ in1,
    const float* __restrict__ wq, const float* __restrict__ bq,
    const float* __restrict__ wk, const float* __restrict__ bk,
    const float* __restrict__ wv, const float* __restrict__ bv,
    __bf16* __restrict__ Vcm, __bf16* __restrict__ Kpm, __bf16* __restrict__ Qpm)
{
    const int t = threadIdx.x;
    const int which = blockIdx.z % 3;
    const int b = blockIdx.z / 3;
    const float* X = (which == 2 ? in1 : in0) + (size_t)b * C_ * NN;
    const float* Wm = which == 0 ? wq : (which == 1 ? wk : wv);
    const float* bias = which == 0 ? bq : (which == 1 ? bk : bv);
    const int o0 = blockIdx.y * 32;
    const int p = blockIdx.x * 512 + t;

    __shared__ float Wl[32][256];
    for (int idx = t; idx < 32 * 256; idx += 256)
        Wl[idx >> 8][idx & 255] = Wm[(size_t)(o0 + (idx >> 8)) * 256 + (idx & 255)];
    __syncthreads();

    float acc0[32], acc1[32];
#pragma unroll
    for (int o = 0; o < 32; ++o) { acc0[o] = 0.f; acc1[o] = 0.f; }

    for (int c = 0; c < 256; c += 4) {
        float xa[4], xb[4];
#pragma unroll
        for (int j = 0; j < 4; ++j) {
            xa[j] = X[(c + j) * NN + p];
            xb[j] = X[(c + j) * NN + p + 256];
        }
#pragma unroll
        for (int o = 0; o < 32; ++o) {
            const float4 w = *(const float4*)&Wl[o][c];
            acc0[o] += w.x * xa[0] + w.y * xa[1] + w.z * xa[2] + w.w * xa[3];
            acc1[o] += w.x * xb[0] + w.y * xb[1] + w.z * xb[2] + w.w * xb[3];
        }
    }
    if (which == 0) {
        // V ch-major bf16
#pragma unroll
        for (int o = 0; o < 32; ++o) {
            const float bo = bias[o0 + o];
            __bf16* dst = Vcm + ((size_t)(b * CH_ + o0 + o)) * NN;
            dst[p] = (__bf16)(acc0[o] + bo);
            dst[p + 256] = (__bf16)(acc1[o] + bo);
        }
    } else {
        __bf16* base = (which == 1 ? Kpm : Qpm);
        __bf16 t0[32], t1[32];
#pragma unroll
        for (int o = 0; o < 32; ++o) {
            const float bo = bias[o0 + o];
            t0[o] = (__bf16)(acc0[o] + bo);
            t1[o] = (__bf16)(acc1[o] + bo);
        }
        __bf16* d0 = base + ((size_t)(b * NN + p)) * CH_ + o0;
        __bf16* d1 = d0 + 256 * CH_;
#pragma unroll
        for (int s = 0; s < 4; ++s) {
            *(uint4*)(d0 + s * 8) = ((const uint4*)t0)[s];
            *(uint4*)(d1 + s * 8) = ((const uint4*)t1)[s];
        }
    }
}

// ---------------------------------------------------------------------------
// Kernel 2: MFMA bf16 flash attention.
// S[j][k] = sum_i K[i][j] Q[i][k]  (A = K pos-major rows, B = Q pos-major rows)
// P = softmax_j(S); O[i][k] = sum_j V[i][j] P[j][k]  (A = V ch-major rows, B = P)
// Block = 32 queries, 4 waves split the 64 KV tiles (16 each), LDS merge.
// grid 512 (XCD-aware decode), block 256.
// ---------------------------------------------------------------------------
__global__ __launch_bounds__(256, 2) void attn_mfma_kernel(
    const __bf16* __restrict__ Qpm, const __bf16* __restrict__ Kpm,
    const __bf16* __restrict__ Vcm, float* __restrict__ x0)
{
    __shared__ float Op[4][128][32];   // 64 KB partial O per wave
    __shared__ float Ml[4][32], Ll[4][32];

    const int t = threadIdx.x;
    const int lane = t & 63;
    const int w = t >> 6;
    const int l31 = lane & 31;
    const int hi = lane >> 5;

    const int bid = blockIdx.x;
    const int xcd = bid & 7;
    const int b = xcd >> 1;                      // 2 XCDs per batch -> K/V L2-resident
    const int qt = (xcd & 1) * 64 + (bid >> 3);  // 0..127
    const int q0 = qt * 32;

    // Q B-fragments in registers (8 i-chunks of 16)
    const __bf16* Qb = Qpm + ((size_t)(b * NN + q0 + l31)) * CH_ + hi * 8;
    bf16x8 qf[8];
#pragma unroll
    for (int ic = 0; ic < 8; ++ic) qf[ic] = *(const bf16x8*)(Qb + ic * 16);

    const __bf16* Kb = Kpm + (size_t)b * NN * CH_;
    const __bf16* Vb = Vcm + (size_t)b * CH_ * NN;

    f32x16 oacc[4];
#pragma unroll
    for (int i = 0; i < 4; ++i)
#pragma unroll
        for (int e = 0; e < 16; ++e) oacc[i][e] = 0.f;

    float m = -3e38f, lsum = 0.f;

    for (int jt = 0; jt < 16; ++jt) {
        const int j0 = (w * 16 + jt) * 64;
        f32x16 s0, s1;
#pragma unroll
        for (int e = 0; e < 16; ++e) { s0[e] = 0.f; s1[e] = 0.f; }
        const __bf16* Kt = Kb + (size_t)(j0 + l31) * CH_ + hi * 8;
#pragma unroll
        for (int ic = 0; ic < 8; ++ic) {
            bf16x8 kf0 = *(const bf16x8*)(Kt + ic * 16);
            bf16x8 kf1 = *(const bf16x8*)(Kt + 32 * CH_ + ic * 16);
            s0 = __builtin_amdgcn_mfma_f32_32x32x16_bf16(kf0, qf[ic], s0, 0, 0, 0);
            s1 = __builtin_amdgcn_mfma_f32_32x32x16_bf16(kf1, qf[ic], s1, 0, 0, 0);
        }
        // ---- online softmax over j (lane-local rows + partner half) ----
        float pm = s0[0];
#pragma unroll
        for (int e = 1; e < 16; ++e) pm = fmaxf(pm, s0[e]);
#pragma unroll
        for (int e = 0; e < 16; ++e) pm = fmaxf(pm, s1[e]);
        pm = fmaxf(pm, __shfl_xor(pm, 32));
        const float mn = fmaxf(m, pm);
        const float al = __expf(m - mn);
        m = mn;
        float ps = 0.f;
#pragma unroll
        for (int e = 0; e < 16; ++e) {
            s0[e] = __expf(s0[e] - mn); ps += s0[e];
            s1[e] = __expf(s1[e] - mn); ps += s1[e];
        }
        ps += __shfl_xor(ps, 32);
        lsum = lsum * al + ps;
#pragma unroll
        for (int i = 0; i < 4; ++i)
#pragma unroll
            for (int e = 0; e < 16; ++e) oacc[i][e] *= al;

        // ---- P (f32, C-layout) -> bf16 B-fragments (4 j-chunks of 16) ----
        u32 pf[4][4];
        {
            u32 wv[8], pw[8];
#pragma unroll
            for (int r = 0; r < 8; ++r) {
                union { __bf16 h[2]; u32 u; } x;
                x.h[0] = (__bf16)s0[2 * r]; x.h[1] = (__bf16)s0[2 * r + 1];
                wv[r] = x.u;
            }
#pragma unroll
            for (int r = 0; r < 8; ++r) pw[r] = (u32)__shfl_xor((int)wv[r], 32);
            pf[0][0] = hi ? pw[2] : wv[0];
            pf[0][1] = hi ? pw[3] : wv[1];
            pf[0][2] = hi ? wv[2] : pw[0];
            pf[0][3] = hi ? wv[3] : pw[1];
            pf[1][0] = hi ? pw[6] : wv[4];
            pf[1][1] = hi ? pw[7] : wv[5];
            pf[1][2] = hi ? wv[6] : pw[4];
            pf[1][3] = hi ? wv[7] : pw[5];
#pragma unroll
            for (int r = 0; r < 8; ++r) {
                union { __bf16 h[2]; u32 u; } x;
                x.h[0] = (__bf16)s1[2 * r]; x.h[1] = (__bf16)s1[2 * r + 1];
                wv[r] = x.u;
            }
#pragma unroll
            for (int r = 0; r < 8; ++r) pw[r] = (u32)__shfl_xor((int)wv[r], 32);
            pf[2][0] = hi ? pw[2] : wv[0];
            pf[2][1] = hi ? pw[3] : wv[1];
            pf[2][2] = hi ? wv[2] : pw[0];
            pf[2][3] = hi ? wv[3] : pw[1];
            pf[3][0] = hi ? pw[6] : wv[4];
            pf[3][1] = hi ? pw[7] : wv[5];
            pf[3][2] = hi ? wv[6] : pw[4];
            pf[3][3] = hi ? wv[7] : pw[5];
        }
        // ---- PV: O[i][k] += V[i][j] P[j][k] ----
        const __bf16* Vt = Vb + (size_t)l31 * NN + j0 + hi * 8;
#pragma unroll
        for (int icf = 0; icf < 4; ++icf) {
#pragma unroll
            for (int jc = 0; jc < 4; ++jc) {
                bf16x8 vf = *(const bf16x8*)(Vt + (size_t)(icf * 32) * NN + jc * 16);
                union { u32 u[4]; bf16x8 v; } cv;
#pragma unroll
                for (int q = 0; q < 4; ++q) cv.u[q] = pf[jc][q];
                oacc[icf] = __builtin_amdgcn_mfma_f32_32x32x16_bf16(vf, cv.v, oacc[icf], 0, 0, 0);
            }
        }
    }

    // ---- write per-wave partials, merge across the 4 KV-split waves ----
#pragma unroll
    for (int icf = 0; icf < 4; ++icf)
#pragma unroll
        for (int q = 0; q < 16; ++q) {
            const int row = icf * 32 + (q & 3) + 8 * (q >> 2) + 4 * hi;
            Op[w][row][l31] = oacc[icf][q];
        }
    if (hi == 0) { Ml[w][l31] = m; Ll[w][l31] = lsum; }
    __syncthreads();
    {
        const int q = t & 31;
        const int i0 = (t >> 5) * 16;
        const float m0 = Ml[0][q], m1 = Ml[1][q], m2 = Ml[2][q], m3 = Ml[3][q];
        const float ms = fmaxf(fmaxf(m0, m1), fmaxf(m2, m3));
        const float a0 = __expf(m0 - ms), a1 = __expf(m1 - ms);
        const float a2 = __expf(m2 - ms), a3 = __expf(m3 - ms);
        const float den = a0 * Ll[0][q] + a1 * Ll[1][q] + a2 * Ll[2][q] + a3 * Ll[3][q];
        const float inv = 1.f / den;
        float* dst = x0 + ((size_t)b * CH_) * NN + q0 + q;
#pragma unroll
        for (int ii = 0; ii < 16; ++ii) {
            const int i = i0 + ii;
            const float num = a0 * Op[0][i][q] + a1 * Op[1][i][q]
                            + a2 * Op[2][i][q] + a3 * Op[3][i][q];
            dst[(size_t)i * NN] = num * inv;
        }
    }
}

// ---------------------------------------------------------------------------
// Kernel 3: conv_o (1x1, 128->256) + BN + GELU -> x0g (fp32 NCHW)
// ---------------------------------------------------------------------------
__global__ __launch_bounds__(256) void convo_kernel(
    const float* __restrict__ x0, const float* __restrict__ wo,
    const float* __restrict__ bo,
    const float* __restrict__ g, const float* __restrict__ bb,
    const float* __restrict__ mm, const float* __restrict__ vv,
    float* __restrict__ x0g)
{
    const int t = threadIdx.x;
    const int b = blockIdx.z;
    const int o0 = blockIdx.y * 32;
    const int p = blockIdx.x * 512 + t;
    const float* X = x0 + (size_t)b * CH_ * NN;

    __shared__ float Wl[32][128];
    for (int idx = t; idx < 32 * 128; idx += 256)
        Wl[idx >> 7][idx & 127] = wo[(size_t)(o0 + (idx >> 7)) * 128 + (idx & 127)];
    __syncthreads();

    float acc0[32], acc1[32];
#pragma unroll
    for (int o = 0; o < 32; ++o) { acc0[o] = 0.f; acc1[o] = 0.f; }

    for (int c = 0; c < 128; c += 4) {
        float xa[4], xb[4];
#pragma unroll
        for (int j = 0; j < 4; ++j) {
            xa[j] = X[(c + j) * NN + p];
            xb[j] = X[(c + j) * NN + p + 256];
        }
#pragma unroll
        for (int o = 0; o < 32; ++o) {
            const float4 w = *(const float4*)&Wl[o][c];
            acc0[o] += w.x * xa[0] + w.y * xa[1] + w.z * xa[2] + w.w * xa[3];
            acc1[o] += w.x * xb[0] + w.y * xb[1] + w.z * xb[2] + w.w * xb[3];
        }
    }
#pragma unroll
    for (int o = 0; o < 32; ++o) {
        const int og = o0 + o;
        const float sc = g[og] * rsqrtf(vv[og] + 1e-5f);
        const float sh = bb[og] - mm[og] * sc;
        const float r0 = (acc0[o] + bo[og]) * sc + sh;
        const float r1 = (acc1[o] + bo[og]) * sc + sh;
        x0g[(size_t)(b * C_ + og) * NN + p] = gelu_erf(r0);
        x0g[(size_t)(b * C_ + og) * NN + p + 256] = gelu_erf(r1);
    }
}

// ---------------------------------------------------------------------------
// Kernel 4: NCHW fp32 -> NHWC bf16 cast/transpose (dst row width 512)
// ---------------------------------------------------------------------------
__global__ __launch_bounds__(256) void nhwc_cast_kernel(
    const float* __restrict__ src, __bf16* __restrict__ dst, int colbase)
{
    __shared__ float Lt[64][65];
    const int t = threadIdx.x;
    const int p0 = blockIdx.x * 64;
    const int c0 = blockIdx.y * 64;
    const int b  = blockIdx.z;
#pragma unroll
    for (int i = 0; i < 16; ++i) {
        int idx = t + i * 256;
        int c = idx >> 6, p = idx & 63;
        Lt[c][p] = src[((size_t)(b * 256 + c0 + c)) * 4096 + p0 + p];
    }
    __syncthreads();
#pragma unroll
    for (int i = 0; i < 16; ++i) {
        int idx = t + i * 256;
        int p = idx >> 6, c = idx & 63;
        dst[((size_t)(b * 4096 + p0 + p)) * 512 + colbase + c0 + c] = (__bf16)Lt[c][p];
    }
}

// ---------------------------------------------------------------------------
// Kernel 5: weight transform: [O][I][3][3] fp32 -> [k9][O][I] bf16
// ---------------------------------------------------------------------------
__global__ __launch_bounds__(256) void wtrans_kernel(
    const float* __restrict__ w0, const float* __restrict__ w1,
    __bf16* __restrict__ Wt0, __bf16* __restrict__ Wt1)
{
    int id = blockIdx.x * 256 + threadIdx.x;
    if (id < 256 * 512) {
        int o = id >> 9, ci = id & 511;
        const float* s = w0 + (size_t)id * 9;
#pragma unroll
        for (int k = 0; k < 9; ++k)
            Wt0[((size_t)k * 256 + o) * 512 + ci] = (__bf16)s[k];
    } else {
        int id2 = id - 256 * 512;
        if (id2 < 256 * 256) {
            int o = id2 >> 8, ci = id2 & 255;
            const float* s = w1 + (size_t)id2 * 9;
#pragma unroll
            for (int k = 0; k < 9; ++k)
                Wt1[((size_t)k * 256 + o) * 256 + ci] = (__bf16)s[k];
        }
    }
}

// ---------------------------------------------------------------------------
// Kernel 6: 3x3 conv via MFMA (implicit GEMM), NHWC bf16 in/out, BN+GELU.
// ---------------------------------------------------------------------------
template<int IC>
__global__ __launch_bounds__(256) void conv3x3_mfma_kernel(
    const __bf16* __restrict__ Xsrc,   // NHWC [4][4096][IC]
    const __bf16* __restrict__ Wt,     // [9][256][IC]
    const float* __restrict__ bias, const float* __restrict__ bng,
    const float* __restrict__ bnb, const float* __restrict__ bnm,
    const float* __restrict__ bnv,
    __bf16* __restrict__ out)          // NHWC [4][4096][256]
{
    constexpr int NC = IC / 16;
    __shared__ __align__(16) char Wl[2][18432];
    __shared__ __align__(16) char Tl[2][13824];
    __shared__ float scb[64], shb[64], bsb[64];

    const int t = threadIdx.x;
    const int bid = blockIdx.x;
    const int xcd = bid & 7, local = bid >> 3;
    const int combo = xcd * 2 + (local >> 4);
    const int pt = local & 15;
    const int m = combo & 3, b = combo >> 2;
    const int o0 = m * 64;
    const int y0 = pt * 4;

    if (t < 64) {
        const int o = o0 + t;
        const float sc = bng[o] * rsqrtf(bnv[o] + 1e-5f);
        scb[t] = sc; shb[t] = bnb[o] - bnm[o] * sc; bsb[t] = bias[o];
    }

    const int lane = t & 63, w = t >> 6;
    const int l31 = lane & 31, hi = lane >> 5;

    uint4 wreg[5], ireg[3];

    auto loadW = [&](int c0) {
#pragma unroll
        for (int s = 0; s < 5; ++s) {
            int u = t + s * 256;
            if (u < 1152) {
                int g = u & 1, o = (u >> 1) & 63, k9 = u >> 7;
                wreg[s] = *(const uint4*)&Wt[((size_t)(k9 * 256 + o0 + o)) * IC + c0 + g * 8];
            }
        }
    };
    auto loadI = [&](int c0) {
#pragma unroll
        for (int s = 0; s < 3; ++s) {
            int u = t + s * 256;
            int g = u & 1, x = (u >> 1) & 63, r = u >> 7;
            int yy = y0 - 1 + r;
            if (yy >= 0 && yy < 64)
                ireg[s] = *(const uint4*)&Xsrc[((size_t)(b * 4096 + yy * 64 + x)) * IC + c0 + g * 8];
            else
                ireg[s] = make_uint4(0u, 0u, 0u, 0u);
        }
    };
    auto writeW = [&](char* dst) {
#pragma unroll
        for (int s = 0; s < 5; ++s) {
            int u = t + s * 256;
            if (u < 1152) {
                int g = u & 1, o = (u >> 1) & 63, k9 = u >> 7;
                int byte = ((k9 * 64 + o) * 32 + g * 16) ^ ((o & 7) << 4);
                *(uint4*)(dst + byte) = wreg[s];
            }
        }
    };
    auto writeI = [&](char* dst) {
#pragma unroll
        for (int s = 0; s < 3; ++s) {
            int u = t + s * 256;
            int g = u & 1, x = (u >> 1) & 63, r = u >> 7;
            int xh = x + 1;
            int byte = (r * 2304 + xh * 32 + g * 16) ^ ((xh & 7) << 4);
            *(uint4*)(dst + byte) = ireg[s];
        }
        if (t < 24) {
            int g = t & 1, side = (t >> 1) & 1, r = t >> 2;
            int xh = side ? 65 : 0;
            int byte = (r * 2304 + xh * 32 + g * 16) ^ ((xh & 7) << 4);
            *(uint4*)(dst + byte) = make_uint4(0u, 0u, 0u, 0u);
        }
    };

    f32x16 acc[2][2];
#pragma unroll
    for (int i = 0; i < 2; ++i)
#pragma unroll
        for (int j = 0; j < 2; ++j)
#pragma unroll
            for (int e = 0; e < 16; ++e) acc[i][j][e] = 0.f;

    const int Abase = (l31 * 32 + hi * 16) ^ ((l31 & 7) << 4);
    int Bbase[3];
#pragma unroll
    for (int dx = 0; dx < 3; ++dx) {
        int xh = dx + l31;
        Bbase[dx] = (xh * 32 + hi * 16) ^ ((xh & 7) << 4);
    }

    auto compute = [&](const char* Wb, const char* Tb) {
#pragma unroll
        for (int k9 = 0; k9 < 9; ++k9) {
            const int dy = k9 / 3, dx = k9 % 3;
            bf16x8 a0 = *(const bf16x8*)(Wb + k9 * 2048 + Abase);
            bf16x8 a1 = *(const bf16x8*)(Wb + k9 * 2048 + 1024 + Abase);
            const char* Trow = Tb + (w + dy) * 2304;
#pragma unroll
            for (int nx = 0; nx < 2; ++nx) {
                bf16x8 bv = *(const bf16x8*)(Trow + nx * 1024 + Bbase[dx]);
                acc[0][nx] = __builtin_amdgcn_mfma_f32_32x32x16_bf16(a0, bv, acc[0][nx], 0, 0, 0);
                acc[1][nx] = __builtin_amdgcn_mfma_f32_32x32x16_bf16(a1, bv, acc[1][nx], 0, 0, 0);
            }
        }
    };

    loadW(0); loadI(0);
    writeW(Wl[0]); writeI(Tl[0]);
    __syncthreads();
    for (int c = 0; c < NC; ++c) {
        const int cur = c & 1;
        if (c + 1 < NC) { loadW((c + 1) * 16); loadI((c + 1) * 16); }
        compute(Wl[cur], Tl[cur]);
        __syncthreads();
        if (c + 1 < NC) { writeW(Wl[cur ^ 1]); writeI(Tl[cur ^ 1]); }
        __syncthreads();
    }

#pragma unroll
    for (int mi = 0; mi < 2; ++mi)
#pragma unroll
        for (int nx = 0; nx < 2; ++nx) {
            const int x = nx * 32 + l31;
            const int p = (y0 + w) * 64 + x;
            const size_t rowbase = ((size_t)(b * 4096 + p)) * 256 + o0;
#pragma unroll
            for (int q = 0; q < 4; ++q) {
                const int obase = mi * 32 + q * 8 + hi * 4;
                __bf16 pk[4];
#pragma unroll
                for (int j = 0; j < 4; ++j) {
                    float v = acc[mi][nx][q * 4 + j] + bsb[obase + j];
                    v = v * scb[obase + j] + shb[obase + j];
                    pk[j] = (__bf16)gelu_erf(v);
                }
                *(uint2*)&out[rowbase + obase] = *(const uint2*)pk;
            }
        }
}

// ---------------------------------------------------------------------------
// Kernel 7/8: global max of (y1 + x0gelu) over spatial, two stages
// ---------------------------------------------------------------------------
__global__ __launch_bounds__(256) void maxpart_kernel(
    const __bf16* __restrict__ y1, const __bf16* __restrict__ xt0,
    float* __restrict__ part)
{
    const int o = threadIdx.x;
    const int chunk = blockIdx.x & 63;
    const int b = blockIdx.x >> 6;
    float mx = -1e30f;
    for (int pp = 0; pp < 64; ++pp) {
        int p = chunk * 64 + pp;
        float a = (float)y1[((size_t)(b * 4096 + p)) * 256 + o];
        float c = (float)xt0[((size_t)(b * 4096 + p)) * 512 + o];
        mx = fmaxf(mx, a + c);
    }
    part[((size_t)(b * 64 + chunk)) * 256 + o] = mx;
}

__global__ __launch_bounds__(256) void maxfin_kernel(
    const float* __restrict__ part, float* __restrict__ out)
{
    const int o = threadIdx.x;
    const int b = blockIdx.x;
    float mx = -1e30f;
    for (int c = 0; c < 64; ++c)
        mx = fmaxf(mx, part[((size_t)(b * 64 + c)) * 256 + o]);
    out[b * 256 + o] = mx;
}

// ---------------------------------------------------------------------------
extern "C" void kernel_launch(void* const* d_in, const int* in_sizes, int n_in,
                              void* d_out, int out_size, void* d_ws, size_t ws_size,
                              hipStream_t stream)
{
    const float* in0  = (const float*)d_in[0];
    const float* in1  = (const float*)d_in[1];
    const float* w_q  = (const float*)d_in[2];
    const float* b_q  = (const float*)d_in[3];
    const float* w_k  = (const float*)d_in[4];
    const float* b_k  = (const float*)d_in[5];
    const float* w_v  = (const float*)d_in[6];
    const float* b_v  = (const float*)d_in[7];
    const float* w_o  = (const float*)d_in[8];
    const float* b_o  = (const float*)d_in[9];
    const float* bn0g = (const float*)d_in[10];
    const float* bn0b = (const float*)d_in[11];
    const float* bn0m = (const float*)d_in[12];
    const float* bn0v = (const float*)d_in[13];
    const float* cbw0 = (const float*)d_in[14];
    const float* cbb0 = (const float*)d_in[15];
    const float* cb0g = (const float*)d_in[16];
    const float* cb0b = (const float*)d_in[17];
    const float* cb0m = (const float*)d_in[18];
    const float* cb0v = (const float*)d_in[19];
    const float* cbw1 = (const float*)d_in[20];
    const float* cbb1 = (const float*)d_in[21];
    const float* cb1g = (const float*)d_in[22];
    const float* cb1b = (const float*)d_in[23];
    const float* cb1m = (const float*)d_in[24];
    const float* cb1v = (const float*)d_in[25];

    char* wsb = (char*)d_ws;
    __bf16* Qpm = (__bf16*)(wsb + 0);                    // [4][4096][128] 4MB
    __bf16* Kpm = (__bf16*)(wsb + ((size_t)4 << 20));    // 4MB
    __bf16* Vcm = (__bf16*)(wsb + ((size_t)8 << 20));    // [4][128][4096] 4MB
    float*  x0  = (float*)(wsb + ((size_t)12 << 20));    // [4][128][4096] 8MB
    float*  x0g = (float*)(wsb + ((size_t)20 << 20));    // [4][256][4096] 16MB
    // bf16 stage (overlays regions dead by the time they're written)
    __bf16* Xt0 = (__bf16*)(wsb + 0);                    // [4][4096][512] 16MB (after attn+convo)
    __bf16* y0  = (__bf16*)(wsb + ((size_t)16 << 20));   // [4][4096][256] 8MB (after casts)
    __bf16* y1  = (__bf16*)(wsb + ((size_t)24 << 20));   // 8MB
    __bf16* Wt0 = (__bf16*)(wsb + ((size_t)36 << 20));   // 2.25MB
    __bf16* Wt1 = (__bf16*)(wsb + ((size_t)36 << 20) + 2359296);
    float*  part = (float*)(wsb + ((size_t)36 << 20) + 2359296 + 1179648);
    float* outp = (float*)d_out;

    proj3_kernel<<<dim3(8, 4, 12), 256, 0, stream>>>(in0, in1, w_q, b_q, w_k, b_k, w_v, b_v, Vcm, Kpm, Qpm);
    attn_mfma_kernel<<<512, 256, 0, stream>>>(Qpm, Kpm, Vcm, x0);
    convo_kernel<<<dim3(8, 8, 4), 256, 0, stream>>>(x0, w_o, b_o, bn0g, bn0b, bn0m, bn0v, x0g);
    wtrans_kernel<<<768, 256, 0, stream>>>(cbw0, cbw1, Wt0, Wt1);
    nhwc_cast_kernel<<<dim3(64, 4, 4), 256, 0, stream>>>(in0, Xt0, 256);
    nhwc_cast_kernel<<<dim3(64, 4, 4), 256, 0, stream>>>(x0g, Xt0, 0);
    conv3x3_mfma_kernel<512><<<256, 256, 0, stream>>>(Xt0, Wt0, cbb0, cb0g, cb0b, cb0m, cb0v, y0);
    conv3x3_mfma_kernel<256><<<256, 256, 0, stream>>>(y0, Wt1, cbb1, cb1g, cb1b, cb1m, cb1v, y1);
    maxpart_kernel<<<256, 256, 0, stream>>>(y1, Xt0, part);
    maxfin_kernel<<<4, 256, 0, stream>>>(part, outp);
}

// Round 4
// 373.709 us; speedup vs baseline: 5.1216x; 1.2192x over previous
//
#include <hip/hip_runtime.h>
#include <math.h>

#define B_ 4
#define C_ 256
#define CH_ 128
#define NN 4096   // H*W = 64*64

typedef __bf16 bf16x8 __attribute__((ext_vector_type(8)));
typedef float f32x16 __attribute__((ext_vector_type(16)));
typedef unsigned int u32;

__device__ __forceinline__ float gelu_erf(float x) {
    return 0.5f * x * (1.0f + erff(x * 0.7071067811865476f));
}

// ---------------------------------------------------------------------------
// NCHW fp32 -> NHWC bf16 cast/transpose. dst row stride and column base are
// parameters so in0 can land directly in Xt0's cols 256-511.
// grid (64 p-tiles, 4 c-tiles, 4 b), block 256
// ---------------------------------------------------------------------------
__global__ __launch_bounds__(256) void nhwc_cast_kernel(
    const float* __restrict__ src, __bf16* __restrict__ dst,
    int colbase, int rowstride)
{
    __shared__ float Lt[64][65];
    const int t = threadIdx.x;
    const int p0 = blockIdx.x * 64;
    const int c0 = blockIdx.y * 64;
    const int b  = blockIdx.z;
#pragma unroll
    for (int i = 0; i < 16; ++i) {
        int idx = t + i * 256;
        int c = idx >> 6, p = idx & 63;
        Lt[c][p] = src[((size_t)(b * 256 + c0 + c)) * 4096 + p0 + p];
    }
    __syncthreads();
#pragma unroll
    for (int i = 0; i < 16; ++i) {
        int idx = t + i * 256;
        int p = idx >> 6, c = idx & 63;
        dst[((size_t)(b * 4096 + p0 + p)) * rowstride + colbase + c0 + c] = (__bf16)Lt[c][p];
    }
}

// ---------------------------------------------------------------------------
// Weight transform: conv3x3 weights -> [k9][O][I] bf16; 1x1 weights -> bf16 copy
// grid 1280, block 256  (131072 + 65536 + 4*32768 ids)
// ---------------------------------------------------------------------------
__global__ __launch_bounds__(256) void wtrans_kernel(
    const float* __restrict__ w0, const float* __restrict__ w1,
    const float* __restrict__ wq, const float* __restrict__ wk,
    const float* __restrict__ wv, const float* __restrict__ wo,
    __bf16* __restrict__ Wt0, __bf16* __restrict__ Wt1,
    __bf16* __restrict__ wqb, __bf16* __restrict__ wkb,
    __bf16* __restrict__ wvb, __bf16* __restrict__ wob)
{
    int id = blockIdx.x * 256 + threadIdx.x;
    if (id < 131072) {
        int o = id >> 9, ci = id & 511;
        const float* s = w0 + (size_t)id * 9;
#pragma unroll
        for (int k = 0; k < 9; ++k)
            Wt0[((size_t)k * 256 + o) * 512 + ci] = (__bf16)s[k];
    } else if (id < 196608) {
        int id2 = id - 131072;
        int o = id2 >> 8, ci = id2 & 255;
        const float* s = w1 + (size_t)id2 * 9;
#pragma unroll
        for (int k = 0; k < 9; ++k)
            Wt1[((size_t)k * 256 + o) * 256 + ci] = (__bf16)s[k];
    } else {
        int id3 = id - 196608;     // 0..131071
        int sel = id3 >> 15;
        int k = id3 & 32767;
        const float* s = sel == 0 ? wq : sel == 1 ? wk : sel == 2 ? wv : wo;
        __bf16* d = sel == 0 ? wqb : sel == 1 ? wkb : sel == 2 ? wvb : wob;
        d[k] = (__bf16)s[k];
    }
}

// ---------------------------------------------------------------------------
// 1x1 projections via MFMA. C[o][p] = sum_c W[o][c] X[p][c] + bias.
// which: 0 -> V (w_q on in0, ch-major out via LDS transpose)
//        1 -> K (w_k on in0, pos-major out)
//        2 -> Q (w_v on in1, pos-major out)
// block 256 = 4 waves (2o x 2p of 64x64 tiles); grid (32, 1, 12)
// ---------------------------------------------------------------------------
__global__ __launch_bounds__(256) void proj_mfma_kernel(
    const __bf16* __restrict__ Xt0,   // [4][4096][512], in0 at cols 256-511
    const __bf16* __restrict__ Xin1,  // [4][4096][256]
    const __bf16* __restrict__ wqb, const __bf16* __restrict__ wkb,
    const __bf16* __restrict__ wvb,
    const float* __restrict__ bq, const float* __restrict__ bk,
    const float* __restrict__ bv,
    __bf16* __restrict__ Vcm, __bf16* __restrict__ Kpm, __bf16* __restrict__ Qpm)
{
    __shared__ __align__(16) __bf16 Vt[4][64][80];
    __shared__ float biasl[128];

    const int t = threadIdx.x;
    const int which = blockIdx.z % 3;
    const int b = blockIdx.z / 3;
    const int p0 = blockIdx.x * 128;

    const __bf16* W = which == 0 ? wqb : which == 1 ? wkb : wvb;
    const float* bias = which == 0 ? bq : which == 1 ? bk : bv;
    const __bf16* src; int stride, colb;
    if (which == 2) { src = Xin1 + (size_t)b * NN * 256; stride = 256; colb = 0; }
    else            { src = Xt0  + (size_t)b * NN * 512; stride = 512; colb = 256; }

    if (t < 128) biasl[t] = bias[t];
    __syncthreads();

    const int lane = t & 63, w = t >> 6;
    const int l31 = lane & 31, hi = lane >> 5;
    const int wo2 = w >> 1, wp2 = w & 1;
    const int ob = wo2 * 64;
    const int pb = p0 + wp2 * 64;

    f32x16 acc[2][2];
#pragma unroll
    for (int i = 0; i < 2; ++i)
#pragma unroll
        for (int j = 0; j < 2; ++j)
#pragma unroll
            for (int e = 0; e < 16; ++e) acc[i][j][e] = 0.f;

#pragma unroll
    for (int kc = 0; kc < 16; ++kc) {
        bf16x8 a0 = *(const bf16x8*)&W[(size_t)(ob + l31) * 256 + hi * 8 + kc * 16];
        bf16x8 a1 = *(const bf16x8*)&W[(size_t)(ob + 32 + l31) * 256 + hi * 8 + kc * 16];
        bf16x8 b0 = *(const bf16x8*)&src[(size_t)(pb + l31) * stride + colb + hi * 8 + kc * 16];
        bf16x8 b1 = *(const bf16x8*)&src[(size_t)(pb + 32 + l31) * stride + colb + hi * 8 + kc * 16];
        acc[0][0] = __builtin_amdgcn_mfma_f32_32x32x16_bf16(a0, b0, acc[0][0], 0, 0, 0);
        acc[0][1] = __builtin_amdgcn_mfma_f32_32x32x16_bf16(a0, b1, acc[0][1], 0, 0, 0);
        acc[1][0] = __builtin_amdgcn_mfma_f32_32x32x16_bf16(a1, b0, acc[1][0], 0, 0, 0);
        acc[1][1] = __builtin_amdgcn_mfma_f32_32x32x16_bf16(a1, b1, acc[1][1], 0, 0, 0);
    }

    if (which) {
        __bf16* dst = (which == 1 ? Kpm : Qpm) + (size_t)b * NN * CH_;
#pragma unroll
        for (int mi = 0; mi < 2; ++mi)
#pragma unroll
            for (int nx = 0; nx < 2; ++nx) {
                const int p = pb + nx * 32 + l31;
#pragma unroll
                for (int q4 = 0; q4 < 4; ++q4) {
                    const int og = ob + mi * 32 + q4 * 8 + hi * 4;
                    __bf16 pk[4];
#pragma unroll
                    for (int j = 0; j < 4; ++j)
                        pk[j] = (__bf16)(acc[mi][nx][q4 * 4 + j] + biasl[og + j]);
                    *(uint2*)&dst[(size_t)p * CH_ + og] = *(const uint2*)pk;
                }
            }
    } else {
        // V: transpose through LDS, write ch-major coalesced
#pragma unroll
        for (int mi = 0; mi < 2; ++mi)
#pragma unroll
            for (int nx = 0; nx < 2; ++nx) {
                const int ploc = nx * 32 + l31;
#pragma unroll
                for (int q4 = 0; q4 < 4; ++q4) {
                    const int oloc = mi * 32 + q4 * 8 + hi * 4;
#pragma unroll
                    for (int j = 0; j < 4; ++j)
                        Vt[w][oloc + j][ploc] =
                            (__bf16)(acc[mi][nx][q4 * 4 + j] + biasl[ob + oloc + j]);
                }
            }
        __syncthreads();
#pragma unroll
        for (int s = 0; s < 8; ++s) {
            const int lin = s * 64 + lane;
            const int row = lin >> 3, ch = lin & 7;
            *(uint4*)&Vcm[((size_t)(b * CH_ + ob + row)) * NN + pb + ch * 8] =
                *(const uint4*)&Vt[w][row][ch * 8];
        }
    }
}

// ---------------------------------------------------------------------------
// MFMA bf16 flash attention, KV-split 8 (4 in-block waves x 2 block-halves).
// Each wave: 32 queries x 8 KV tiles of 64 keys. In-block LDS merge (bf16),
// per-block partial (O,m,l) to workspace; attn_merge combines the 2 halves.
// grid 1024, block 256.
// ---------------------------------------------------------------------------
__global__ __launch_bounds__(256, 2) void attn_mfma_kernel(
    const __bf16* __restrict__ Qpm, const __bf16* __restrict__ Kpm,
    const __bf16* __restrict__ Vcm,
    __bf16* __restrict__ Opart, float* __restrict__ Mpart, float* __restrict__ Lpart)
{
    __shared__ __bf16 Op[4][128][34];   // 34816 B
    __shared__ float Ml[4][32], Ll[4][32];

    const int t = threadIdx.x;
    const int lane = t & 63;
    const int w = t >> 6;
    const int l31 = lane & 31;
    const int hi = lane >> 5;

    const int bid = blockIdx.x;
    const int xcd = bid & 7;
    const int b = xcd >> 1;                      // 2 XCDs per batch
    const int local = bid >> 3;                  // 0..127
    const int qt = (xcd & 1) * 64 + (local & 63);
    const int half = local >> 6;
    const int q0 = qt * 32;

    // Q B-fragments in registers (8 i-chunks of 16)
    const __bf16* Qb = Qpm + ((size_t)(b * NN + q0 + l31)) * CH_ + hi * 8;
    bf16x8 qf[8];
#pragma unroll
    for (int ic = 0; ic < 8; ++ic) qf[ic] = *(const bf16x8*)(Qb + ic * 16);

    const __bf16* Kb = Kpm + (size_t)b * NN * CH_;
    const __bf16* Vb = Vcm + (size_t)b * CH_ * NN;

    f32x16 oacc[4];
#pragma unroll
    for (int i = 0; i < 4; ++i)
#pragma unroll
        for (int e = 0; e < 16; ++e) oacc[i][e] = 0.f;

    float m = -3e38f, lsum = 0.f;

    for (int jt = 0; jt < 8; ++jt) {
        const int j0 = (half * 32 + w * 8 + jt) * 64;
        f32x16 s0, s1;
#pragma unroll
        for (int e = 0; e < 16; ++e) { s0[e] = 0.f; s1[e] = 0.f; }
        const __bf16* Kt = Kb + (size_t)(j0 + l31) * CH_ + hi * 8;
        __builtin_amdgcn_s_setprio(1);
#pragma unroll
        for (int ic = 0; ic < 8; ++ic) {
            bf16x8 kf0 = *(const bf16x8*)(Kt + ic * 16);
            bf16x8 kf1 = *(const bf16x8*)(Kt + 32 * CH_ + ic * 16);
            s0 = __builtin_amdgcn_mfma_f32_32x32x16_bf16(kf0, qf[ic], s0, 0, 0, 0);
            s1 = __builtin_amdgcn_mfma_f32_32x32x16_bf16(kf1, qf[ic], s1, 0, 0, 0);
        }
        __builtin_amdgcn_s_setprio(0);
        // ---- online softmax over j: tree max, defer-max rescale ----
        float tm[16];
#pragma unroll
        for (int e = 0; e < 16; ++e) tm[e] = fmaxf(s0[e], s1[e]);
#pragma unroll
        for (int off = 8; off > 0; off >>= 1)
#pragma unroll
            for (int e = 0; e < off; ++e) tm[e] = fmaxf(tm[e], tm[e + off]);
        const float pm = fmaxf(tm[0], __shfl_xor(tm[0], 32));
        if (!__all(pm <= m + 8.f)) {
            const float mn = fmaxf(m, pm);
            const float al = __expf(m - mn);
            m = mn;
            lsum *= al;
#pragma unroll
            for (int i = 0; i < 4; ++i)
#pragma unroll
                for (int e = 0; e < 16; ++e) oacc[i][e] *= al;
        }
        float ts[16];
#pragma unroll
        for (int e = 0; e < 16; ++e) {
            s0[e] = __expf(s0[e] - m);
            s1[e] = __expf(s1[e] - m);
            ts[e] = s0[e] + s1[e];
        }
#pragma unroll
        for (int off = 8; off > 0; off >>= 1)
#pragma unroll
            for (int e = 0; e < off; ++e) ts[e] += ts[e + off];
        lsum += ts[0] + __shfl_xor(ts[0], 32);

        // ---- P (f32, C-layout) -> bf16 B-fragments (4 j-chunks of 16) ----
        u32 pf[4][4];
        {
            u32 wv[8], pw[8];
#pragma unroll
            for (int r = 0; r < 8; ++r) {
                union { __bf16 h[2]; u32 u; } x;
                x.h[0] = (__bf16)s0[2 * r]; x.h[1] = (__bf16)s0[2 * r + 1];
                wv[r] = x.u;
            }
#pragma unroll
            for (int r = 0; r < 8; ++r) pw[r] = (u32)__shfl_xor((int)wv[r], 32);
            pf[0][0] = hi ? pw[2] : wv[0];
            pf[0][1] = hi ? pw[3] : wv[1];
            pf[0][2] = hi ? wv[2] : pw[0];
            pf[0][3] = hi ? wv[3] : pw[1];
            pf[1][0] = hi ? pw[6] : wv[4];
            pf[1][1] = hi ? pw[7] : wv[5];
            pf[1][2] = hi ? wv[6] : pw[4];
            pf[1][3] = hi ? wv[7] : pw[5];
#pragma unroll
            for (int r = 0; r < 8; ++r) {
                union { __bf16 h[2]; u32 u; } x;
                x.h[0] = (__bf16)s1[2 * r]; x.h[1] = (__bf16)s1[2 * r + 1];
                wv[r] = x.u;
            }
#pragma unroll
            for (int r = 0; r < 8; ++r) pw[r] = (u32)__shfl_xor((int)wv[r], 32);
            pf[2][0] = hi ? pw[2] : wv[0];
            pf[2][1] = hi ? pw[3] : wv[1];
            pf[2][2] = hi ? wv[2] : pw[0];
            pf[2][3] = hi ? wv[3] : pw[1];
            pf[3][0] = hi ? pw[6] : wv[4];
            pf[3][1] = hi ? pw[7] : wv[5];
            pf[3][2] = hi ? wv[6] : pw[4];
            pf[3][3] = hi ? wv[7] : pw[5];
        }
        // ---- PV: O[i][k] += V[i][j] P[j][k] ----
        const __bf16* Vt = Vb + (size_t)l31 * NN + j0 + hi * 8;
        __builtin_amdgcn_s_setprio(1);
#pragma unroll
        for (int icf = 0; icf < 4; ++icf) {
#pragma unroll
            for (int jc = 0; jc < 4; ++jc) {
                bf16x8 vf = *(const bf16x8*)(Vt + (size_t)(icf * 32) * NN + jc * 16);
                union { u32 u[4]; bf16x8 v; } cv;
#pragma unroll
                for (int q = 0; q < 4; ++q) cv.u[q] = pf[jc][q];
                oacc[icf] = __builtin_amdgcn_mfma_f32_32x32x16_bf16(vf, cv.v, oacc[icf], 0, 0, 0);
            }
        }
        __builtin_amdgcn_s_setprio(0);
    }

    // ---- in-block merge across the 4 split-waves (bf16 partials) ----
#pragma unroll
    for (int icf = 0; icf < 4; ++icf)
#pragma unroll
        for (int q = 0; q < 16; ++q) {
            const int row = icf * 32 + (q & 3) + 8 * (q >> 2) + 4 * hi;
            Op[w][row][l31] = (__bf16)oacc[icf][q];
        }
    if (hi == 0) { Ml[w][l31] = m; Ll[w][l31] = lsum; }
    __syncthreads();
    {
        const int q = t & 31;
        const int i0g = (t >> 5) * 16;
        const float m0 = Ml[0][q], m1 = Ml[1][q], m2 = Ml[2][q], m3 = Ml[3][q];
        const float ms = fmaxf(fmaxf(m0, m1), fmaxf(m2, m3));
        const float a0 = __expf(m0 - ms), a1 = __expf(m1 - ms);
        const float a2 = __expf(m2 - ms), a3 = __expf(m3 - ms);
        const float den = a0 * Ll[0][q] + a1 * Ll[1][q] + a2 * Ll[2][q] + a3 * Ll[3][q];
        union { __bf16 h[16]; uint4 u4[2]; } pk;
#pragma unroll
        for (int ii = 0; ii < 16; ++ii) {
            const int i = i0g + ii;
            pk.h[ii] = (__bf16)(a0 * (float)Op[0][i][q] + a1 * (float)Op[1][i][q]
                              + a2 * (float)Op[2][i][q] + a3 * (float)Op[3][i][q]);
        }
        const size_t base = ((size_t)((half * 4 + b) * NN) + q0 + q) * CH_ + i0g;
        *(uint4*)&Opart[base] = pk.u4[0];
        *(uint4*)&Opart[base + 8] = pk.u4[1];
        if (t < 32) {
            Mpart[(size_t)(half * 4 + b) * NN + q0 + q] = ms;
            Lpart[(size_t)(half * 4 + b) * NN + q0 + q] = den;
        }
    }
}

// ---------------------------------------------------------------------------
// Merge the 2 KV-half partials -> x0 bf16 pos-major [4][4096][128]
// grid 256, block 256 (thread = one 32-i chunk of one query)
// ---------------------------------------------------------------------------
__global__ __launch_bounds__(256) void attn_merge_kernel(
    const __bf16* __restrict__ Opart, const float* __restrict__ Mpart,
    const float* __restrict__ Lpart, __bf16* __restrict__ x0)
{
    const int id = blockIdx.x * 256 + threadIdx.x;   // 65536
    const int qg = id >> 2;
    const int i0 = (id & 3) * 32;
    const int b = qg >> 12, q = qg & 4095;
    const size_t idx0 = (size_t)b * NN + q;
    const size_t idx1 = (size_t)(4 + b) * NN + q;
    const float m0 = Mpart[idx0], m1 = Mpart[idx1];
    const float ms = fmaxf(m0, m1);
    const float a0 = __expf(m0 - ms), a1 = __expf(m1 - ms);
    const float inv = 1.f / (a0 * Lpart[idx0] + a1 * Lpart[idx1]);
    const __bf16* O0 = &Opart[idx0 * CH_ + i0];
    const __bf16* O1 = &Opart[idx1 * CH_ + i0];
    union { __bf16 h[32]; uint4 u4[4]; } ov;
#pragma unroll
    for (int ii = 0; ii < 32; ++ii)
        ov.h[ii] = (__bf16)((a0 * (float)O0[ii] + a1 * (float)O1[ii]) * inv);
    uint4* dst = (uint4*)&x0[((size_t)b * NN + q) * CH_ + i0];
#pragma unroll
    for (int s = 0; s < 4; ++s) dst[s] = ov.u4[s];
}

// ---------------------------------------------------------------------------
// conv_o (1x1, 128->256) via MFMA + BN + GELU -> Xt0 cols 0-255 (NHWC bf16)
// block 256 = 4 waves (2o x 2p); grid (32, 2, 4)
// ---------------------------------------------------------------------------
__global__ __launch_bounds__(256) void convo_mfma_kernel(
    const __bf16* __restrict__ x0, const __bf16* __restrict__ wob,
    const float* __restrict__ bo,
    const float* __restrict__ g, const float* __restrict__ bb,
    const float* __restrict__ mm, const float* __restrict__ vv,
    __bf16* __restrict__ Xt0)
{
    __shared__ float scb[128], shb[128], bsb[128];
    const int t = threadIdx.x;
    const int p0 = blockIdx.x * 128;
    const int o0 = blockIdx.y * 128;
    const int b = blockIdx.z;
    if (t < 128) {
        const int o = o0 + t;
        const float sc = g[o] * rsqrtf(vv[o] + 1e-5f);
        scb[t] = sc; shb[t] = bb[o] - mm[o] * sc; bsb[t] = bo[o];
    }
    __syncthreads();

    const int lane = t & 63, w = t >> 6;
    const int l31 = lane & 31, hi = lane >> 5;
    const int wo2 = w >> 1, wp2 = w & 1;
    const int ob = o0 + wo2 * 64;
    const int pb = p0 + wp2 * 64;

    f32x16 acc[2][2];
#pragma unroll
    for (int i = 0; i < 2; ++i)
#pragma unroll
        for (int j = 0; j < 2; ++j)
#pragma unroll
            for (int e = 0; e < 16; ++e) acc[i][j][e] = 0.f;

#pragma unroll
    for (int kc = 0; kc < 8; ++kc) {
        bf16x8 a0 = *(const bf16x8*)&wob[(size_t)(ob + l31) * 128 + hi * 8 + kc * 16];
        bf16x8 a1 = *(const bf16x8*)&wob[(size_t)(ob + 32 + l31) * 128 + hi * 8 + kc * 16];
        bf16x8 b0 = *(const bf16x8*)&x0[((size_t)(b * NN) + pb + l31) * 128 + hi * 8 + kc * 16];
        bf16x8 b1 = *(const bf16x8*)&x0[((size_t)(b * NN) + pb + 32 + l31) * 128 + hi * 8 + kc * 16];
        acc[0][0] = __builtin_amdgcn_mfma_f32_32x32x16_bf16(a0, b0, acc[0][0], 0, 0, 0);
        acc[0][1] = __builtin_amdgcn_mfma_f32_32x32x16_bf16(a0, b1, acc[0][1], 0, 0, 0);
        acc[1][0] = __builtin_amdgcn_mfma_f32_32x32x16_bf16(a1, b0, acc[1][0], 0, 0, 0);
        acc[1][1] = __builtin_amdgcn_mfma_f32_32x32x16_bf16(a1, b1, acc[1][1], 0, 0, 0);
    }

#pragma unroll
    for (int mi = 0; mi < 2; ++mi)
#pragma unroll
        for (int nx = 0; nx < 2; ++nx) {
            const int p = pb + nx * 32 + l31;
            const size_t rowbase = ((size_t)(b * NN) + p) * 512 + o0;
#pragma unroll
            for (int q4 = 0; q4 < 4; ++q4) {
                const int ol = wo2 * 64 + mi * 32 + q4 * 8 + hi * 4;
                __bf16 pk[4];
#pragma unroll
                for (int j = 0; j < 4; ++j) {
                    float v = acc[mi][nx][q4 * 4 + j] + bsb[ol + j];
                    v = v * scb[ol + j] + shb[ol + j];
                    pk[j] = (__bf16)gelu_erf(v);
                }
                *(uint2*)&Xt0[rowbase + ol] = *(const uint2*)pk;
            }
        }
}

// ---------------------------------------------------------------------------
// 3x3 conv via MFMA (implicit GEMM), NHWC bf16 in/out, BN+GELU. (unchanged)
// ---------------------------------------------------------------------------
template<int IC>
__global__ __launch_bounds__(256) void conv3x3_mfma_kernel(
    const __bf16* __restrict__ Xsrc,   // NHWC [4][4096][IC]
    const __bf16* __restrict__ Wt,     // [9][256][IC]
    const float* __restrict__ bias, const float* __restrict__ bng,
    const float* __restrict__ bnb, const float* __restrict__ bnm,
    const float* __restrict__ bnv,
    __bf16* __restrict__ out)          // NHWC [4][4096][256]
{
    constexpr int NC = IC / 16;
    __shared__ __align__(16) char Wl[2][18432];
    __shared__ __align__(16) char Tl[2][13824];
    __shared__ float scb[64], shb[64], bsb[64];

    const int t = threadIdx.x;
    const int bid = blockIdx.x;
    const int xcd = bid & 7, local = bid >> 3;
    const int combo = xcd * 2 + (local >> 4);
    const int pt = local & 15;
    const int m = combo & 3, b = combo >> 2;
    const int o0 = m * 64;
    const int y0 = pt * 4;

    if (t < 64) {
        const int o = o0 + t;
        const float sc = bng[o] * rsqrtf(bnv[o] + 1e-5f);
        scb[t] = sc; shb[t] = bnb[o] - bnm[o] * sc; bsb[t] = bias[o];
    }

    const int lane = t & 63, w = t >> 6;
    const int l31 = lane & 31, hi = lane >> 5;

    uint4 wreg[5], ireg[3];

    auto loadW = [&](int c0) {
#pragma unroll
        for (int s = 0; s < 5; ++s) {
            int u = t + s * 256;
            if (u < 1152) {
                int g = u & 1, o = (u >> 1) & 63, k9 = u >> 7;
                wreg[s] = *(const uint4*)&Wt[((size_t)(k9 * 256 + o0 + o)) * IC + c0 + g * 8];
            }
        }
    };
    auto loadI = [&](int c0) {
#pragma unroll
        for (int s = 0; s < 3; ++s) {
            int u = t + s * 256;
            int g = u & 1, x = (u >> 1) & 63, r = u >> 7;
            int yy = y0 - 1 + r;
            if (yy >= 0 && yy < 64)
                ireg[s] = *(const uint4*)&Xsrc[((size_t)(b * 4096 + yy * 64 + x)) * IC + c0 + g * 8];
            else
                ireg[s] = make_uint4(0u, 0u, 0u, 0u);
        }
    };
    auto writeW = [&](char* dst) {
#pragma unroll
        for (int s = 0; s < 5; ++s) {
            int u = t + s * 256;
            if (u < 1152) {
                int g = u & 1, o = (u >> 1) & 63, k9 = u >> 7;
                int byte = ((k9 * 64 + o) * 32 + g * 16) ^ ((o & 7) << 4);
                *(uint4*)(dst + byte) = wreg[s];
            }
        }
    };
    auto writeI = [&](char* dst) {
#pragma unroll
        for (int s = 0; s < 3; ++s) {
            int u = t + s * 256;
            int g = u & 1, x = (u >> 1) & 63, r = u >> 7;
            int xh = x + 1;
            int byte = (r * 2304 + xh * 32 + g * 16) ^ ((xh & 7) << 4);
            *(uint4*)(dst + byte) = ireg[s];
        }
        if (t < 24) {
            int g = t & 1, side = (t >> 1) & 1, r = t >> 2;
            int xh = side ? 65 : 0;
            int byte = (r * 2304 + xh * 32 + g * 16) ^ ((xh & 7) << 4);
            *(uint4*)(dst + byte) = make_uint4(0u, 0u, 0u, 0u);
        }
    };

    f32x16 acc[2][2];
#pragma unroll
    for (int i = 0; i < 2; ++i)
#pragma unroll
        for (int j = 0; j < 2; ++j)
#pragma unroll
            for (int e = 0; e < 16; ++e) acc[i][j][e] = 0.f;

    const int Abase = (l31 * 32 + hi * 16) ^ ((l31 & 7) << 4);
    int Bbase[3];
#pragma unroll
    for (int dx = 0; dx < 3; ++dx) {
        int xh = dx + l31;
        Bbase[dx] = (xh * 32 + hi * 16) ^ ((xh & 7) << 4);
    }

    auto compute = [&](const char* Wb, const char* Tb) {
#pragma unroll
        for (int k9 = 0; k9 < 9; ++k9) {
            const int dy = k9 / 3, dx = k9 % 3;
            bf16x8 a0 = *(const bf16x8*)(Wb + k9 * 2048 + Abase);
            bf16x8 a1 = *(const bf16x8*)(Wb + k9 * 2048 + 1024 + Abase);
            const char* Trow = Tb + (w + dy) * 2304;
#pragma unroll
            for (int nx = 0; nx < 2; ++nx) {
                bf16x8 bv = *(const bf16x8*)(Trow + nx * 1024 + Bbase[dx]);
                acc[0][nx] = __builtin_amdgcn_mfma_f32_32x32x16_bf16(a0, bv, acc[0][nx], 0, 0, 0);
                acc[1][nx] = __builtin_amdgcn_mfma_f32_32x32x16_bf16(a1, bv, acc[1][nx], 0, 0, 0);
            }
        }
    };

    loadW(0); loadI(0);
    writeW(Wl[0]); writeI(Tl[0]);
    __syncthreads();
    for (int c = 0; c < NC; ++c) {
        const int cur = c & 1;
        if (c + 1 < NC) { loadW((c + 1) * 16); loadI((c + 1) * 16); }
        compute(Wl[cur], Tl[cur]);
        __syncthreads();
        if (c + 1 < NC) { writeW(Wl[cur ^ 1]); writeI(Tl[cur ^ 1]); }
        __syncthreads();
    }

#pragma unroll
    for (int mi = 0; mi < 2; ++mi)
#pragma unroll
        for (int nx = 0; nx < 2; ++nx) {
            const int x = nx * 32 + l31;
            const int p = (y0 + w) * 64 + x;
            const size_t rowbase = ((size_t)(b * 4096 + p)) * 256 + o0;
#pragma unroll
            for (int q = 0; q < 4; ++q) {
                const int obase = mi * 32 + q * 8 + hi * 4;
                __bf16 pk[4];
#pragma unroll
                for (int j = 0; j < 4; ++j) {
                    float v = acc[mi][nx][q * 4 + j] + bsb[obase + j];
                    v = v * scb[obase + j] + shb[obase + j];
                    pk[j] = (__bf16)gelu_erf(v);
                }
                *(uint2*)&out[rowbase + obase] = *(const uint2*)pk;
            }
        }
}

// ---------------------------------------------------------------------------
// global max of (y1 + x0gelu) over spatial, two stages
// ---------------------------------------------------------------------------
__global__ __launch_bounds__(256) void maxpart_kernel(
    const __bf16* __restrict__ y1, const __bf16* __restrict__ xt0,
    float* __restrict__ part)
{
    const int o = threadIdx.x;
    const int chunk = blockIdx.x & 63;
    const int b = blockIdx.x >> 6;
    float mx = -1e30f;
    for (int pp = 0; pp < 64; ++pp) {
        int p = chunk * 64 + pp;
        float a = (float)y1[((size_t)(b * 4096 + p)) * 256 + o];
        float c = (float)xt0[((size_t)(b * 4096 + p)) * 512 + o];
        mx = fmaxf(mx, a + c);
    }
    part[((size_t)(b * 64 + chunk)) * 256 + o] = mx;
}

__global__ __launch_bounds__(256) void maxfin_kernel(
    const float* __restrict__ part, float* __restrict__ out)
{
    const int o = threadIdx.x;
    const int b = blockIdx.x;
    float mx = -1e30f;
    for (int c = 0; c < 64; ++c)
        mx = fmaxf(mx, part[((size_t)(b * 64 + c)) * 256 + o]);
    out[b * 256 + o] = mx;
}

// ---------------------------------------------------------------------------
extern "C" void kernel_launch(void* const* d_in, const int* in_sizes, int n_in,
                              void* d_out, int out_size, void* d_ws, size_t ws_size,
                              hipStream_t stream)
{
    const float* in0  = (const float*)d_in[0];
    const float* in1  = (const float*)d_in[1];
    const float* w_q  = (const float*)d_in[2];
    const float* b_q  = (const float*)d_in[3];
    const float* w_k  = (const float*)d_in[4];
    const float* b_k  = (const float*)d_in[5];
    const float* w_v  = (const float*)d_in[6];
    const float* b_v  = (const float*)d_in[7];
    const float* w_o  = (const float*)d_in[8];
    const float* b_o  = (const float*)d_in[9];
    const float* bn0g = (const float*)d_in[10];
    const float* bn0b = (const float*)d_in[11];
    const float* bn0m = (const float*)d_in[12];
    const float* bn0v = (const float*)d_in[13];
    const float* cbw0 = (const float*)d_in[14];
    const float* cbb0 = (const float*)d_in[15];
    const float* cb0g = (const float*)d_in[16];
    const float* cb0b = (const float*)d_in[17];
    const float* cb0m = (const float*)d_in[18];
    const float* cb0v = (const float*)d_in[19];
    const float* cbw1 = (const float*)d_in[20];
    const float* cbb1 = (const float*)d_in[21];
    const float* cb1g = (const float*)d_in[22];
    const float* cb1b = (const float*)d_in[23];
    const float* cb1m = (const float*)d_in[24];
    const float* cb1v = (const float*)d_in[25];

    char* wsb = (char*)d_ws;
    const size_t MB = 1u << 20;
    // 0-16MB:   Xt0 [4][4096][512] bf16 (cols 0-255 convo out, 256-511 in0)
    // 16-24MB:  Xin1 [4][4096][256] bf16; dead after proj -> Opart [2][4][4096][128] bf16
    // 24-32MB:  Qpm, Kpm [4][4096][128] bf16; dead after attn -> y0 [4][4096][256] bf16
    // 32-40MB:  Vcm [4][128][4096] bf16 + x0 [4][4096][128] bf16; -> y1 after convo
    // 40MB+:    weights bf16, Mpart/Lpart, part
    __bf16* Xt0  = (__bf16*)(wsb);
    __bf16* Xin1 = (__bf16*)(wsb + 16 * MB);
    __bf16* Opart= (__bf16*)(wsb + 16 * MB);
    __bf16* Qpm  = (__bf16*)(wsb + 24 * MB);
    __bf16* Kpm  = (__bf16*)(wsb + 28 * MB);
    __bf16* y0   = (__bf16*)(wsb + 24 * MB);
    __bf16* Vcm  = (__bf16*)(wsb + 32 * MB);
    __bf16* x0   = (__bf16*)(wsb + 36 * MB);
    __bf16* y1   = (__bf16*)(wsb + 32 * MB);
    __bf16* wqb  = (__bf16*)(wsb + 40 * MB);
    __bf16* wkb  = (__bf16*)(wsb + 40 * MB + 65536);
    __bf16* wvb  = (__bf16*)(wsb + 40 * MB + 2 * 65536);
    __bf16* wob  = (__bf16*)(wsb + 40 * MB + 3 * 65536);
    __bf16* Wt0  = (__bf16*)(wsb + 40 * MB + 4 * 65536);              // 2359296 B
    __bf16* Wt1  = (__bf16*)(wsb + 40 * MB + 4 * 65536 + 2359296);    // 1179648 B
    float*  Mpart= (float*)(wsb + 44 * MB);                            // 128KB
    float*  Lpart= (float*)(wsb + 44 * MB + 131072);                   // 128KB
    float*  part = (float*)(wsb + 44 * MB + 2 * 131072);               // 256KB
    float* outp = (float*)d_out;

    nhwc_cast_kernel<<<dim3(64, 4, 4), 256, 0, stream>>>(in0, Xt0, 256, 512);
    nhwc_cast_kernel<<<dim3(64, 4, 4), 256, 0, stream>>>(in1, Xin1, 0, 256);
    wtrans_kernel<<<1280, 256, 0, stream>>>(cbw0, cbw1, w_q, w_k, w_v, w_o,
                                            Wt0, Wt1, wqb, wkb, wvb, wob);
    proj_mfma_kernel<<<dim3(32, 1, 12), 256, 0, stream>>>(
        Xt0, Xin1, wqb, wkb, wvb, b_q, b_k, b_v, Vcm, Kpm, Qpm);
    attn_mfma_kernel<<<1024, 256, 0, stream>>>(Qpm, Kpm, Vcm, Opart, Mpart, Lpart);
    attn_merge_kernel<<<256, 256, 0, stream>>>(Opart, Mpart, Lpart, x0);
    convo_mfma_kernel<<<dim3(32, 2, 4), 256, 0, stream>>>(
        x0, wob, b_o, bn0g, bn0b, bn0m, bn0v, Xt0);
    conv3x3_mfma_kernel<512><<<256, 256, 0, stream>>>(Xt0, Wt0, cbb0, cb0g, cb0b, cb0m, cb0v, y0);
    conv3x3_mfma_kernel<256><<<256, 256, 0, stream>>>(y0, Wt1, cbb1, cb1g, cb1b, cb1m, cb1v, y1);
    maxpart_kernel<<<256, 256, 0, stream>>>(y1, Xt0, part);
    maxfin_kernel<<<4, 256, 0, stream>>>(part, outp);
}